// Round 17
// baseline (2303.979 us; speedup 1.0000x reference)
//
#include <hip/hip_runtime.h>

typedef unsigned short u16;
typedef unsigned int   u32;
typedef __bf16 bf16x8 __attribute__((ext_vector_type(8)));
typedef float  f32x4  __attribute__((ext_vector_type(4)));
typedef unsigned short u16x2 __attribute__((ext_vector_type(2)));
typedef unsigned short u16x4 __attribute__((ext_vector_type(4)));
typedef unsigned short u16x8 __attribute__((ext_vector_type(8)));
typedef unsigned int   u32x4 __attribute__((ext_vector_type(4)));

#define DEV __device__ __forceinline__

DEV u16 f2b(float f) {                      // f32 -> bf16 RNE
  u32 u = __builtin_bit_cast(u32, f);
  return (u16)((u + 0x7fffu + ((u >> 16) & 1u)) >> 16);
}
DEV float b2f(u16 h) { u32 u = ((u32)h) << 16; return __builtin_bit_cast(float, u); }

DEV void gload16(const void* g, void* l) {  // async global->LDS, 16B/lane
  __builtin_amdgcn_global_load_lds((__attribute__((address_space(1))) void*)(g),
                                   (__attribute__((address_space(3))) void*)(l),
                                   16, 0, 0);
}

DEV f32x4 MFMA(bf16x8 a, bf16x8 b, f32x4 c) {
  return __builtin_amdgcn_mfma_f32_16x16x32_bf16(a, b, c, 0, 0, 0);
}

DEV u32 ldsoff(const void* p) {             // LDS byte offset for ds_* asm
  return (u32)(uintptr_t)(__attribute__((address_space(3))) void*)p;
}
DEV bf16x8 dsr128(u32 a) {                  // compiler-opaque LDS read
  u32x4 d;
  asm volatile("ds_read_b128 %0, %1" : "=v"(d) : "v"(a) : "memory");
  return __builtin_bit_cast(bf16x8, d);
}

// ---------------------------------------------------------------- transpose+cvt (64x64 tiles, vectorized)
__global__ __launch_bounds__(256) void transpose_cvt(const float* __restrict__ W,
                                                     u16* __restrict__ Wt,
                                                     int K, int N) {
  __shared__ float tile[64][65];
  const int n0 = blockIdx.x * 64, k0 = blockIdx.y * 64;
  const int tx = threadIdx.x, ty = threadIdx.y;  // 64 x 4
#pragma unroll
  for (int i = 0; i < 16; ++i) {
    const int row = ty + i * 4;
    tile[row][tx] = W[(size_t)(k0 + row) * N + n0 + tx];
  }
  __syncthreads();
#pragma unroll
  for (int i = 0; i < 8; ++i) {
    const int nrow = ty * 2 + (tx >> 5) + i * 8;
    const int kp = (tx & 31) * 2;
    u16x2 v;
    v[0] = f2b(tile[kp][nrow]);
    v[1] = f2b(tile[kp + 1][nrow]);
    *(u16x2*)&Wt[(size_t)(n0 + nrow) * K + k0 + kp] = v;
  }
}

// ---------------------------------------------------------------- rmsnorm (f32 in, bf16 out), D=4096
__global__ __launch_bounds__(256) void rmsnorm_k(const float* __restrict__ x,
                                                 const float* __restrict__ w,
                                                 u16* __restrict__ o, int D) {
  const int row = blockIdx.x, tid = threadIdx.x;
  const float4* xr = (const float4*)(x + (size_t)row * D);
  const float4* wr = (const float4*)w;
  float4 v[4];
  float ss = 0.f;
#pragma unroll
  for (int i = 0; i < 4; ++i) {
    v[i] = xr[i * 256 + tid];
    ss += v[i].x * v[i].x + v[i].y * v[i].y + v[i].z * v[i].z + v[i].w * v[i].w;
  }
#pragma unroll
  for (int off = 1; off < 64; off <<= 1) ss += __shfl_xor(ss, off, 64);
  __shared__ float red[4];
  if ((tid & 63) == 0) red[tid >> 6] = ss;
  __syncthreads();
  const float tot = red[0] + red[1] + red[2] + red[3];
  const float sc = rsqrtf(tot / (float)D + 1e-6f);
  u16x4* orow = (u16x4*)(o + (size_t)row * D);
#pragma unroll
  for (int i = 0; i < 4; ++i) {
    float4 wv = wr[i * 256 + tid];
    u16x4 p;
    p[0] = f2b(v[i].x * sc * wv.x);
    p[1] = f2b(v[i].y * sc * wv.y);
    p[2] = f2b(v[i].z * sc * wv.z);
    p[3] = f2b(v[i].w * sc * wv.w);
    orow[i * 256 + tid] = p;
  }
}

// ---------------------------------------------------------------- RoPE table
__global__ __launch_bounds__(256) void rope_table(const int* __restrict__ positions,
                                                  float* __restrict__ tab, int BS) {
  const int idx = blockIdx.x * 256 + threadIdx.x;
  if (idx >= BS * 64) return;
  const int bs = idx >> 6, i = idx & 63;
  const float pos = (float)positions[bs];
  const float inv = __expf(-(float)i * (9.210340371976184f / 64.f));
  const float ang = pos * inv;
  float s, c;
  sincosf(ang, &s, &c);
  tab[idx] = c;
  tab[BS * 64 + idx] = s;
}

// ---------------------------------------------------------------- RoPE in-place on bf16 qkv [BS][12288], u16x2-vectorized
__global__ __launch_bounds__(256) void rope_apply(u16* __restrict__ qkv,
                                                  const float* __restrict__ tab, int BS) {
  const int idx = blockIdx.x * 256 + threadIdx.x;  // (bs, h, i-pair)
  if (idx >= BS * 1024) return;
  const int ip = (idx & 31) * 2, h = (idx >> 5) & 31, bs = idx >> 10;
  const float2 c2 = ((const float2*)tab)[bs * 32 + (ip >> 1)];
  const float2 s2 = ((const float2*)(tab + (size_t)BS * 64))[bs * 32 + (ip >> 1)];
  const size_t base = (size_t)bs * 12288 + h * 128 + ip;
  u16x2 a1 = *(const u16x2*)&qkv[base];
  u16x2 a2 = *(const u16x2*)&qkv[base + 64];
  u16x2 b1 = *(const u16x2*)&qkv[base + 4096];
  u16x2 b2 = *(const u16x2*)&qkv[base + 4096 + 64];
  u16x2 r;
  r[0] = f2b(b2f(a1[0]) * c2.x - b2f(a2[0]) * s2.x);
  r[1] = f2b(b2f(a1[1]) * c2.y - b2f(a2[1]) * s2.y);
  *(u16x2*)&qkv[base] = r;
  r[0] = f2b(b2f(a2[0]) * c2.x + b2f(a1[0]) * s2.x);
  r[1] = f2b(b2f(a2[1]) * c2.y + b2f(a1[1]) * s2.y);
  *(u16x2*)&qkv[base + 64] = r;
  r[0] = f2b(b2f(b1[0]) * c2.x - b2f(b2[0]) * s2.x);
  r[1] = f2b(b2f(b1[1]) * c2.y - b2f(b2[1]) * s2.y);
  *(u16x2*)&qkv[base + 4096] = r;
  r[0] = f2b(b2f(b2[0]) * c2.x + b2f(b1[0]) * s2.x);
  r[1] = f2b(b2f(b2[1]) * c2.y + b2f(b1[1]) * s2.y);
  *(u16x2*)&qkv[base + 4096 + 64] = r;
}

// ---------------------------------------------------------------- GEMM 256x256, BK=32, 8 waves, 4-phase (m201 template)
// Round-15/16 replay-verified: 3-slot ring, chunk swizzle pos = c ^ ((r>>1)&3) (0 conflicts),
// inline-asm ds_read_b128 + rule-18 fence, counted vmcnt(4) with FINAL-ITERATION vmcnt(0) race fix,
// setprio around MFMA, T1 XCD swizzle.
// MODE 0: bf16 out   1: bf16 + f32 bias[col]   2: f32 + f32 resid   3: bf16 g1*silu(acc)
template <int MODE>
__global__ __launch_bounds__(512, 2) void gemm256(const u16* __restrict__ A,
                                                  const u16* __restrict__ Bt,
                                                  void* __restrict__ outp,
                                                  const float* __restrict__ bias,
                                                  const float* __restrict__ resid,
                                                  const u16* __restrict__ g1,
                                                  int M, int N, int K) {
  __shared__ __align__(16) u16 As[3 * 8192];
  __shared__ __align__(16) u16 Bs[3 * 8192];     // 96 KiB total
  const int tid = threadIdx.x;
  const int wid = tid >> 6, l = tid & 63;
  const int wm = wid >> 2, wn = wid & 3;          // 2 x 4 waves, each owns 128x64
  const int lr = l & 15, lc = l >> 4;
  // T1 XCD-aware bijective swizzle (all grids: nwg % 8 == 0)
  const int gx = gridDim.x;
  const int nwg = gx * gridDim.y;
  const int orig = blockIdx.y * gx + blockIdx.x;
  const int wg = (orig & 7) * (nwg >> 3) + (orig >> 3);
  const int m0 = (wg / gx) * 256, n0 = (wg % gx) * 256;

  const int NT = K >> 5;                          // tiles of BK=32; NT even (128 / 344)
  const int NI = NT >> 1;

  const int rt = tid >> 2;
  const int ct = (tid & 3) ^ ((rt >> 1) & 3);
  const u16* aS = A + (size_t)(m0 + rt) * K + ct * 8;
  const u16* bS = Bt + (size_t)(n0 + rt) * K + ct * 8;

  auto STG = [&](u16* slot, const u16* src, int tk) {   // one full 256x32 tile = 2 gloads
    gload16(src + tk * 32, slot + wid * 512);
    gload16(src + (size_t)128 * K + tk * 32, slot + 4096 + wid * 512);
  };

  const u32 aBase = ldsoff(As), bBase = ldsoff(Bs);
  auto offA = [&](int slot, int mf) {
    const int r = wm * 128 + mf * 16 + lr;
    return aBase + (u32)slot * 16384u + (u32)(r * 64 + ((lc ^ ((r >> 1) & 3)) * 16));
  };
  auto offB = [&](int slot, int nf) {
    const int r = wn * 64 + nf * 16 + lr;
    return bBase + (u32)slot * 16384u + (u32)(r * 64 + ((lc ^ ((r >> 1) & 3)) * 16));
  };

  f32x4 acc[8][4] = {};

#define BAR()  asm volatile("s_barrier" ::: "memory")
#define VM4()  asm volatile("s_waitcnt vmcnt(4)" ::: "memory")
#define VM0()  asm volatile("s_waitcnt vmcnt(0)" ::: "memory")
#define LGKM0_FENCE() do { asm volatile("s_waitcnt lgkmcnt(0)" ::: "memory"); \
                           __builtin_amdgcn_sched_barrier(0); } while (0)

  // prologue: T0 -> slot0, T1 -> slot1 (8 loads); T0 landed, T1 in flight
  STG(&As[0], aS, 0);
  STG(&Bs[0], bS, 0);
  STG(&As[8192], aS, 1);
  STG(&Bs[8192], bS, 1);
  VM4();
  BAR();

  int sa = 0, sb = 1, sc = 2;
  for (int i = 0; i < NI; ++i) {
    const int Tc = 2 * i + 2, Td = 2 * i + 3;
    u16* Aa = &As[sa * 8192]; u16* Ba = &Bs[sa * 8192];
    u16* Ac = &As[sc * 8192]; u16* Bc = &Bs[sc * 8192];
    bf16x8 af[8], b0, b1;
    // ---- P1: tile Ta, nf01
#pragma unroll
    for (int mf = 0; mf < 8; ++mf) af[mf] = dsr128(offA(sa, mf));
    b0 = dsr128(offB(sa, 0)); b1 = dsr128(offB(sa, 1));
    if (Tc < NT) STG(Ac, aS, Tc);
    BAR();
    LGKM0_FENCE();
    __builtin_amdgcn_s_setprio(1);
#pragma unroll
    for (int mf = 0; mf < 8; ++mf) {
      acc[mf][0] = MFMA(af[mf], b0, acc[mf][0]);
      acc[mf][1] = MFMA(af[mf], b1, acc[mf][1]);
    }
    __builtin_amdgcn_s_setprio(0);
    BAR();
    // ---- P2: tile Ta, nf23
    b0 = dsr128(offB(sa, 2)); b1 = dsr128(offB(sa, 3));
    if (Tc < NT) STG(Bc, bS, Tc);
    BAR();
    LGKM0_FENCE();
    __builtin_amdgcn_s_setprio(1);
#pragma unroll
    for (int mf = 0; mf < 8; ++mf) {
      acc[mf][2] = MFMA(af[mf], b0, acc[mf][2]);
      acc[mf][3] = MFMA(af[mf], b1, acc[mf][3]);
    }
    __builtin_amdgcn_s_setprio(0);
    if (Tc < NT) VM4(); else VM0();   // RACE FIX: final iter fully drains tile NT-1's loads
    BAR();
    // ---- P3: tile Tb, nf01
#pragma unroll
    for (int mf = 0; mf < 8; ++mf) af[mf] = dsr128(offA(sb, mf));
    b0 = dsr128(offB(sb, 0)); b1 = dsr128(offB(sb, 1));
    if (Td < NT) STG(Aa, aS, Td);
    BAR();
    LGKM0_FENCE();
    __builtin_amdgcn_s_setprio(1);
#pragma unroll
    for (int mf = 0; mf < 8; ++mf) {
      acc[mf][0] = MFMA(af[mf], b0, acc[mf][0]);
      acc[mf][1] = MFMA(af[mf], b1, acc[mf][1]);
    }
    __builtin_amdgcn_s_setprio(0);
    BAR();
    // ---- P4: tile Tb, nf23
    b0 = dsr128(offB(sb, 2)); b1 = dsr128(offB(sb, 3));
    if (Td < NT) STG(Ba, bS, Td);
    BAR();
    LGKM0_FENCE();
    __builtin_amdgcn_s_setprio(1);
#pragma unroll
    for (int mf = 0; mf < 8; ++mf) {
      acc[mf][2] = MFMA(af[mf], b0, acc[mf][2]);
      acc[mf][3] = MFMA(af[mf], b1, acc[mf][3]);
    }
    __builtin_amdgcn_s_setprio(0);
    if (Td < NT) VM4(); else VM0();   // RACE FIX (tail symmetry)
    BAR();
    // rotate slots: next iter (Ta',Tb',Tc') -> (sc, sa, sb)
    const int t = sc; sc = sb; sb = sa; sa = t;
  }
#undef BAR
#undef VM4
#undef VM0
#undef LGKM0_FENCE

#pragma unroll
  for (int mf = 0; mf < 8; ++mf) {
#pragma unroll
    for (int nf = 0; nf < 4; ++nf) {
      const int gr = m0 + wm * 128 + mf * 16 + lc * 4;
      const int gc = n0 + wn * 64 + nf * 16 + lr;
#pragma unroll
      for (int r = 0; r < 4; ++r) {
        float v = acc[mf][nf][r];
        const size_t idx = (size_t)(gr + r) * N + gc;
        if constexpr (MODE == 0) {
          ((u16*)outp)[idx] = f2b(v);
        } else if constexpr (MODE == 1) {
          ((u16*)outp)[idx] = f2b(v + bias[gc]);
        } else if constexpr (MODE == 2) {
          ((float*)outp)[idx] = v + resid[idx];
        } else {
          const float g = b2f(g1[idx]);
          const float sv = v / (1.f + __expf(-v));
          ((u16*)outp)[idx] = f2b(g * sv);
        }
      }
    }
  }
}

// ---------------------------------------------------------------- flash attention (causal), HD=128, QBLK=128, KVBLK=64
// 8 waves x 16 q-rows; staging per q-row halved vs 64-row blocks; K/V L2 traffic halved; grid halved.
// K : Ks[k][d] at el = k*128 + (d ^ ((k&7)*8))
// V : Vt[d][k] at el = (d*64 + k) ^ ((d&7)*8)
// P : Ps[w][q][k] at el = q*64 + (k ^ ((q&7)*8))
// Masking: qb = qtile*8 + w (global 16-row q-block); for kv tile kt, sub-tile ks covers key-block 4*kt+ks.
//   nks = qb - 4*kt + 1 (clamped to 4; <=0 -> wave fully masked this tile); diagonal when ks == qb-4*kt.
__global__ __launch_bounds__(512) void attn_kernel(const u16* __restrict__ qkv,
                                                   u16* __restrict__ o, int S) {
  const int qtile = gridDim.x - 1 - blockIdx.x;   // largest-work blocks first
  const int bh = blockIdx.y;
  const int b = bh >> 5, h = bh & 31;
  const int q0 = qtile * 128;
  const int tid = threadIdx.x;
  const int w = tid >> 6, l = tid & 63;
  const int lr = l & 15, lc = l >> 4;
  const size_t RS = 12288;
  const float SCALE = 0.08838834764831845f;  // 128^-0.5

  __shared__ __align__(16) u16 Ks[64 * 128];
  __shared__ __align__(16) u16 Vt[128 * 64];
  __shared__ __align__(16) u16 Ps[8][16 * 64];

  bf16x8 qf[4];
  {
    const u16* qp = qkv + (size_t)(b * S + q0 + w * 16 + lr) * RS + h * 128 + 8 * lc;
#pragma unroll
    for (int kc = 0; kc < 4; ++kc) qf[kc] = *(const bf16x8*)(qp + kc * 32);
  }

  float m_[4], ls[4];
  f32x4 O[8] = {};
#pragma unroll
  for (int r = 0; r < 4; ++r) { m_[r] = -3e38f; ls[r] = 0.f; }

  const int qb = qtile * 8 + w;                   // global 16-row q-block of this wave
  const int nkt = qtile * 2 + 2;
  for (int kt = 0; kt < nkt; ++kt) {
    const int k0 = kt * 64;
    // ---- stage K: 512 threads, 2 iters, swizzled ds_write_b128
#pragma unroll
    for (int it = 0; it < 2; ++it) {
      const int eid = it * 512 + tid;
      const int kr = eid >> 4, d0 = (eid & 15) * 8;
      u16x8 k8 = *(const u16x8*)(qkv + (size_t)(b * S + k0 + kr) * RS + 4096 + h * 128 + d0);
      *(u16x8*)&Ks[kr * 128 + (d0 ^ ((kr & 7) * 8))] = k8;
    }
    // ---- stage V transposed: lane owns row k0+l, chunk (it*8+w)
#pragma unroll
    for (int it = 0; it < 2; ++it) {
      const int d0 = (it * 8 + w) * 8;
      u16x8 v8 = *(const u16x8*)(qkv + (size_t)(b * S + k0 + l) * RS + 8192 + h * 128 + d0);
#pragma unroll
      for (int jj = 0; jj < 8; ++jj) {
        const int d = d0 + jj;
        Vt[(d * 64 + l) ^ ((d & 7) * 8)] = v8[jj];
      }
    }
    __syncthreads();

    const int nks_raw = qb - kt * 4 + 1;          // sub-tiles this wave needs (may be <=0 or >4)
    const int nks = nks_raw > 4 ? 4 : nks_raw;
    float sv[4][4];
#pragma unroll
    for (int ks = 0; ks < 4; ++ks) {
      if (ks < nks) {
        const int row = ks * 16 + lr;
        f32x4 sacc = {0.f, 0.f, 0.f, 0.f};
#pragma unroll
        for (int kc = 0; kc < 4; ++kc) {
          bf16x8 kf = *(const bf16x8*)&Ks[row * 128 + ((kc * 32 + 8 * lc) ^ ((lr & 7) * 8))];
          sacc = MFMA(qf[kc], kf, sacc);
        }
        const bool dm = (ks == nks_raw - 1);      // diagonal-crossing sub-tile
#pragma unroll
        for (int r = 0; r < 4; ++r) {
          float x = sacc[r] * SCALE;
          if (dm) {
            const int kg = ks * 16 + lr, qg = w * 16 + lc * 4 + r;
            if (k0 + kg > q0 + qg) x = -3e38f;
          }
          sv[ks][r] = x;
        }
      } else {
#pragma unroll
        for (int r = 0; r < 4; ++r) sv[ks][r] = -3e38f;
      }
    }

    float alpha[4];
#pragma unroll
    for (int r = 0; r < 4; ++r) {
      float pm = fmaxf(fmaxf(sv[0][r], sv[1][r]), fmaxf(sv[2][r], sv[3][r]));
#pragma unroll
      for (int off = 1; off < 16; off <<= 1) pm = fmaxf(pm, __shfl_xor(pm, off, 64));
      const float mn = fmaxf(m_[r], pm);
      alpha[r] = __expf(m_[r] - mn);
      m_[r] = mn;
    }
    float p[4][4];
#pragma unroll
    for (int ks = 0; ks < 4; ++ks)
#pragma unroll
      for (int r = 0; r < 4; ++r) {
        p[ks][r] = __expf(sv[ks][r] - m_[r]);
        const int q = lc * 4 + r, k = ks * 16 + lr;
        Ps[w][q * 64 + (k ^ ((q & 7) * 8))] = f2b(p[ks][r]);
      }
#pragma unroll
    for (int r = 0; r < 4; ++r) {
      float s = p[0][r] + p[1][r] + p[2][r] + p[3][r];
#pragma unroll
      for (int off = 1; off < 16; off <<= 1) s += __shfl_xor(s, off, 64);
      ls[r] = ls[r] * alpha[r] + s;
    }
#pragma unroll
    for (int dt = 0; dt < 8; ++dt)
#pragma unroll
      for (int r = 0; r < 4; ++r) O[dt][r] *= alpha[r];

#pragma unroll
    for (int half = 0; half < 2; ++half) {
      const bf16x8 ap = *(const bf16x8*)&Ps[w][lr * 64 + ((half * 32 + 8 * lc) ^ ((lr & 7) * 8))];
#pragma unroll
      for (int dt = 0; dt < 8; ++dt) {
        const int d = dt * 16 + lr;
        const bf16x8 bv = *(const bf16x8*)&Vt[d * 64 + ((half * 32 + 8 * lc) ^ ((d & 7) * 8))];
        O[dt] = MFMA(ap, bv, O[dt]);
      }
    }
    __syncthreads();
  }

  float inv[4];
#pragma unroll
  for (int r = 0; r < 4; ++r) inv[r] = 1.f / ls[r];
#pragma unroll
  for (int dt = 0; dt < 8; ++dt)
#pragma unroll
    for (int r = 0; r < 4; ++r) {
      const int qg = q0 + w * 16 + lc * 4 + r;
      o[(size_t)(b * S + qg) * 4096 + h * 128 + dt * 16 + lr] = f2b(O[dt][r] * inv[r]);
    }
}

// ---------------------------------------------------------------- launch
extern "C" void kernel_launch(void* const* d_in, const int* in_sizes, int n_in,
                              void* d_out, int out_size, void* d_ws, size_t ws_size,
                              hipStream_t stream) {
  const int*   positions = (const int*)d_in[0];
  const float* hidden    = (const float*)d_in[1];
  const float* ln1       = (const float*)d_in[2];
  const float* ln2       = (const float*)d_in[3];
  const float* Wqkv      = (const float*)d_in[4];
  const float* bqkv      = (const float*)d_in[5];
  const float* Wo        = (const float*)d_in[6];
  const float* W1        = (const float*)d_in[7];
  const float* W2        = (const float*)d_in[8];
  const float* Wout      = (const float*)d_in[9];
  float* out = (float*)d_out;

  const int S = 2048, BS = 4096, D = 4096, FF = 11008, N3 = 12288;

  char* ws = (char*)d_ws;
  size_t off = 0;
  auto alloc = [&](size_t bytes) { void* p = ws + off; off += (bytes + 255) & ~(size_t)255; return p; };
  u16*   WT    = (u16*)alloc((size_t)N3 * D * 2);       // reused for every weight
  u16*   qkv   = (u16*)alloc((size_t)BS * N3 * 2);
  u16*   slotH = (u16*)alloc((size_t)BS * D * 2);       // h / attn_out / h3
  float* h2    = (float*)alloc((size_t)BS * D * 4);
  u16*   slotG = (u16*)alloc((size_t)BS * FF * 2);      // G1 -> act in-place
  float* tab   = (float*)alloc((size_t)2 * BS * 64 * 4);
  if (ws_size < off) return;

  rope_table<<<(BS * 64 + 255) / 256, 256, 0, stream>>>(positions, tab, BS);

  // h = rmsnorm(hidden) ; qkv = h @ Wqkv + b
  transpose_cvt<<<dim3(N3 / 64, D / 64), dim3(64, 4), 0, stream>>>(Wqkv, WT, D, N3);
  rmsnorm_k<<<BS, 256, 0, stream>>>(hidden, ln1, slotH, D);
  gemm256<1><<<dim3(N3 / 256, BS / 256), 512, 0, stream>>>(slotH, WT, qkv, bqkv, nullptr, nullptr, BS, N3, D);
  rope_apply<<<(BS * 1024) / 256, 256, 0, stream>>>(qkv, tab, BS);

  // attention (128 q-rows per block, 8 waves)
  attn_kernel<<<dim3(S / 128, 64), 512, 0, stream>>>(qkv, slotH, S);

  // h2 = hidden + attn @ Wo
  transpose_cvt<<<dim3(D / 64, D / 64), dim3(64, 4), 0, stream>>>(Wo, WT, D, D);
  gemm256<2><<<dim3(D / 256, BS / 256), 512, 0, stream>>>(slotH, WT, h2, nullptr, hidden, nullptr, BS, D, D);

  // h3 = rmsnorm(h2) ; G1 = h3@W1 ; act = G1 * silu(h3@W2) ; out = h2 + act@Wout
  rmsnorm_k<<<BS, 256, 0, stream>>>(h2, ln2, slotH, D);
  transpose_cvt<<<dim3(FF / 64, D / 64), dim3(64, 4), 0, stream>>>(W1, WT, D, FF);
  gemm256<0><<<dim3(FF / 256, BS / 256), 512, 0, stream>>>(slotH, WT, slotG, nullptr, nullptr, nullptr, BS, FF, D);
  transpose_cvt<<<dim3(FF / 64, D / 64), dim3(64, 4), 0, stream>>>(W2, WT, D, FF);
  gemm256<3><<<dim3(FF / 256, BS / 256), 512, 0, stream>>>(slotH, WT, slotG, nullptr, nullptr, slotG, BS, FF, D);
  transpose_cvt<<<dim3(D / 64, FF / 64), dim3(64, 4), 0, stream>>>(Wout, WT, FF, D);
  gemm256<2><<<dim3(D / 256, BS / 256), 512, 0, stream>>>(slotG, WT, out, nullptr, h2, nullptr, BS, D, FF);
}

// Round 18
// 2286.545 us; speedup vs baseline: 1.0076x; 1.0076x over previous
//
#include <hip/hip_runtime.h>

typedef unsigned short u16;
typedef unsigned int   u32;
typedef __bf16 bf16x8 __attribute__((ext_vector_type(8)));
typedef float  f32x4  __attribute__((ext_vector_type(4)));
typedef unsigned short u16x2 __attribute__((ext_vector_type(2)));
typedef unsigned short u16x4 __attribute__((ext_vector_type(4)));
typedef unsigned short u16x8 __attribute__((ext_vector_type(8)));
typedef unsigned int   u32x4 __attribute__((ext_vector_type(4)));

#define DEV __device__ __forceinline__

DEV u16 f2b(float f) {                      // f32 -> bf16 RNE
  u32 u = __builtin_bit_cast(u32, f);
  return (u16)((u + 0x7fffu + ((u >> 16) & 1u)) >> 16);
}
DEV float b2f(u16 h) { u32 u = ((u32)h) << 16; return __builtin_bit_cast(float, u); }

DEV void gload16(const void* g, void* l) {  // async global->LDS, 16B/lane
  __builtin_amdgcn_global_load_lds((__attribute__((address_space(1))) void*)(g),
                                   (__attribute__((address_space(3))) void*)(l),
                                   16, 0, 0);
}

DEV f32x4 MFMA(bf16x8 a, bf16x8 b, f32x4 c) {
  return __builtin_amdgcn_mfma_f32_16x16x32_bf16(a, b, c, 0, 0, 0);
}

DEV u32 ldsoff(const void* p) {             // LDS byte offset for ds_* asm
  return (u32)(uintptr_t)(__attribute__((address_space(3))) void*)p;
}
DEV bf16x8 dsr128(u32 a) {                  // compiler-opaque LDS read
  u32x4 d;
  asm volatile("ds_read_b128 %0, %1" : "=v"(d) : "v"(a) : "memory");
  return __builtin_bit_cast(bf16x8, d);
}

// ---------------------------------------------------------------- transpose+cvt (64x64 tiles, vectorized)
__global__ __launch_bounds__(256) void transpose_cvt(const float* __restrict__ W,
                                                     u16* __restrict__ Wt,
                                                     int K, int N) {
  __shared__ float tile[64][65];
  const int n0 = blockIdx.x * 64, k0 = blockIdx.y * 64;
  const int tx = threadIdx.x, ty = threadIdx.y;  // 64 x 4
#pragma unroll
  for (int i = 0; i < 16; ++i) {
    const int row = ty + i * 4;
    tile[row][tx] = W[(size_t)(k0 + row) * N + n0 + tx];
  }
  __syncthreads();
#pragma unroll
  for (int i = 0; i < 8; ++i) {
    const int nrow = ty * 2 + (tx >> 5) + i * 8;
    const int kp = (tx & 31) * 2;
    u16x2 v;
    v[0] = f2b(tile[kp][nrow]);
    v[1] = f2b(tile[kp + 1][nrow]);
    *(u16x2*)&Wt[(size_t)(n0 + nrow) * K + k0 + kp] = v;
  }
}

// ---------------------------------------------------------------- rmsnorm (f32 in, bf16 out), D=4096
__global__ __launch_bounds__(256) void rmsnorm_k(const float* __restrict__ x,
                                                 const float* __restrict__ w,
                                                 u16* __restrict__ o, int D) {
  const int row = blockIdx.x, tid = threadIdx.x;
  const float4* xr = (const float4*)(x + (size_t)row * D);
  const float4* wr = (const float4*)w;
  float4 v[4];
  float ss = 0.f;
#pragma unroll
  for (int i = 0; i < 4; ++i) {
    v[i] = xr[i * 256 + tid];
    ss += v[i].x * v[i].x + v[i].y * v[i].y + v[i].z * v[i].z + v[i].w * v[i].w;
  }
#pragma unroll
  for (int off = 1; off < 64; off <<= 1) ss += __shfl_xor(ss, off, 64);
  __shared__ float red[4];
  if ((tid & 63) == 0) red[tid >> 6] = ss;
  __syncthreads();
  const float tot = red[0] + red[1] + red[2] + red[3];
  const float sc = rsqrtf(tot / (float)D + 1e-6f);
  u16x4* orow = (u16x4*)(o + (size_t)row * D);
#pragma unroll
  for (int i = 0; i < 4; ++i) {
    float4 wv = wr[i * 256 + tid];
    u16x4 p;
    p[0] = f2b(v[i].x * sc * wv.x);
    p[1] = f2b(v[i].y * sc * wv.y);
    p[2] = f2b(v[i].z * sc * wv.z);
    p[3] = f2b(v[i].w * sc * wv.w);
    orow[i * 256 + tid] = p;
  }
}

// ---------------------------------------------------------------- RoPE table
__global__ __launch_bounds__(256) void rope_table(const int* __restrict__ positions,
                                                  float* __restrict__ tab, int BS) {
  const int idx = blockIdx.x * 256 + threadIdx.x;
  if (idx >= BS * 64) return;
  const int bs = idx >> 6, i = idx & 63;
  const float pos = (float)positions[bs];
  const float inv = __expf(-(float)i * (9.210340371976184f / 64.f));
  const float ang = pos * inv;
  float s, c;
  sincosf(ang, &s, &c);
  tab[idx] = c;
  tab[BS * 64 + idx] = s;
}

// ---------------------------------------------------------------- RoPE in-place on bf16 qkv [BS][12288], u16x2-vectorized
__global__ __launch_bounds__(256) void rope_apply(u16* __restrict__ qkv,
                                                  const float* __restrict__ tab, int BS) {
  const int idx = blockIdx.x * 256 + threadIdx.x;  // (bs, h, i-pair)
  if (idx >= BS * 1024) return;
  const int ip = (idx & 31) * 2, h = (idx >> 5) & 31, bs = idx >> 10;
  const float2 c2 = ((const float2*)tab)[bs * 32 + (ip >> 1)];
  const float2 s2 = ((const float2*)(tab + (size_t)BS * 64))[bs * 32 + (ip >> 1)];
  const size_t base = (size_t)bs * 12288 + h * 128 + ip;
  u16x2 a1 = *(const u16x2*)&qkv[base];
  u16x2 a2 = *(const u16x2*)&qkv[base + 64];
  u16x2 b1 = *(const u16x2*)&qkv[base + 4096];
  u16x2 b2 = *(const u16x2*)&qkv[base + 4096 + 64];
  u16x2 r;
  r[0] = f2b(b2f(a1[0]) * c2.x - b2f(a2[0]) * s2.x);
  r[1] = f2b(b2f(a1[1]) * c2.y - b2f(a2[1]) * s2.y);
  *(u16x2*)&qkv[base] = r;
  r[0] = f2b(b2f(a2[0]) * c2.x + b2f(a1[0]) * s2.x);
  r[1] = f2b(b2f(a2[1]) * c2.y + b2f(a1[1]) * s2.y);
  *(u16x2*)&qkv[base + 64] = r;
  r[0] = f2b(b2f(b1[0]) * c2.x - b2f(b2[0]) * s2.x);
  r[1] = f2b(b2f(b1[1]) * c2.y - b2f(b2[1]) * s2.y);
  *(u16x2*)&qkv[base + 4096] = r;
  r[0] = f2b(b2f(b2[0]) * c2.x + b2f(b1[0]) * s2.x);
  r[1] = f2b(b2f(b2[1]) * c2.y + b2f(b1[1]) * s2.y);
  *(u16x2*)&qkv[base + 4096 + 64] = r;
}

// ---------------------------------------------------------------- GEMM 256x256, BK=32, 8 waves, 4-phase (m201 template)
// Replay-verified (r15/r16): 3-slot ring, chunk swizzle pos = c ^ ((r>>1)&3) (0 conflicts),
// inline-asm ds_read_b128 + rule-18 fence, counted vmcnt(4) with FINAL-ITERATION vmcnt(0) race fix,
// setprio around MFMA, T1 XCD swizzle.
// MODE 0: bf16 out   1: bf16 + f32 bias[col]   2: f32 + f32 resid   3: bf16 g1*silu(acc)
template <int MODE>
__global__ __launch_bounds__(512, 2) void gemm256(const u16* __restrict__ A,
                                                  const u16* __restrict__ Bt,
                                                  void* __restrict__ outp,
                                                  const float* __restrict__ bias,
                                                  const float* __restrict__ resid,
                                                  const u16* __restrict__ g1,
                                                  int M, int N, int K) {
  __shared__ __align__(16) u16 As[3 * 8192];
  __shared__ __align__(16) u16 Bs[3 * 8192];     // 96 KiB total
  const int tid = threadIdx.x;
  const int wid = tid >> 6, l = tid & 63;
  const int wm = wid >> 2, wn = wid & 3;          // 2 x 4 waves, each owns 128x64
  const int lr = l & 15, lc = l >> 4;
  // T1 XCD-aware bijective swizzle (all grids: nwg % 8 == 0)
  const int gx = gridDim.x;
  const int nwg = gx * gridDim.y;
  const int orig = blockIdx.y * gx + blockIdx.x;
  const int wg = (orig & 7) * (nwg >> 3) + (orig >> 3);
  const int m0 = (wg / gx) * 256, n0 = (wg % gx) * 256;

  const int NT = K >> 5;                          // tiles of BK=32; NT even (128 / 344)
  const int NI = NT >> 1;

  const int rt = tid >> 2;
  const int ct = (tid & 3) ^ ((rt >> 1) & 3);
  const u16* aS = A + (size_t)(m0 + rt) * K + ct * 8;
  const u16* bS = Bt + (size_t)(n0 + rt) * K + ct * 8;

  auto STG = [&](u16* slot, const u16* src, int tk) {   // one full 256x32 tile = 2 gloads
    gload16(src + tk * 32, slot + wid * 512);
    gload16(src + (size_t)128 * K + tk * 32, slot + 4096 + wid * 512);
  };

  const u32 aBase = ldsoff(As), bBase = ldsoff(Bs);
  auto offA = [&](int slot, int mf) {
    const int r = wm * 128 + mf * 16 + lr;
    return aBase + (u32)slot * 16384u + (u32)(r * 64 + ((lc ^ ((r >> 1) & 3)) * 16));
  };
  auto offB = [&](int slot, int nf) {
    const int r = wn * 64 + nf * 16 + lr;
    return bBase + (u32)slot * 16384u + (u32)(r * 64 + ((lc ^ ((r >> 1) & 3)) * 16));
  };

  f32x4 acc[8][4] = {};

#define BAR()  asm volatile("s_barrier" ::: "memory")
#define VM4()  asm volatile("s_waitcnt vmcnt(4)" ::: "memory")
#define VM0()  asm volatile("s_waitcnt vmcnt(0)" ::: "memory")
#define LGKM0_FENCE() do { asm volatile("s_waitcnt lgkmcnt(0)" ::: "memory"); \
                           __builtin_amdgcn_sched_barrier(0); } while (0)

  // prologue: T0 -> slot0, T1 -> slot1 (8 loads); T0 landed, T1 in flight
  STG(&As[0], aS, 0);
  STG(&Bs[0], bS, 0);
  STG(&As[8192], aS, 1);
  STG(&Bs[8192], bS, 1);
  VM4();
  BAR();

  int sa = 0, sb = 1, sc = 2;
  for (int i = 0; i < NI; ++i) {
    const int Tc = 2 * i + 2, Td = 2 * i + 3;
    u16* Aa = &As[sa * 8192]; u16* Ba = &Bs[sa * 8192];
    u16* Ac = &As[sc * 8192]; u16* Bc = &Bs[sc * 8192];
    bf16x8 af[8], b0, b1;
    // ---- P1: tile Ta, nf01
#pragma unroll
    for (int mf = 0; mf < 8; ++mf) af[mf] = dsr128(offA(sa, mf));
    b0 = dsr128(offB(sa, 0)); b1 = dsr128(offB(sa, 1));
    if (Tc < NT) STG(Ac, aS, Tc);
    BAR();
    LGKM0_FENCE();
    __builtin_amdgcn_s_setprio(1);
#pragma unroll
    for (int mf = 0; mf < 8; ++mf) {
      acc[mf][0] = MFMA(af[mf], b0, acc[mf][0]);
      acc[mf][1] = MFMA(af[mf], b1, acc[mf][1]);
    }
    __builtin_amdgcn_s_setprio(0);
    BAR();
    // ---- P2: tile Ta, nf23
    b0 = dsr128(offB(sa, 2)); b1 = dsr128(offB(sa, 3));
    if (Tc < NT) STG(Bc, bS, Tc);
    BAR();
    LGKM0_FENCE();
    __builtin_amdgcn_s_setprio(1);
#pragma unroll
    for (int mf = 0; mf < 8; ++mf) {
      acc[mf][2] = MFMA(af[mf], b0, acc[mf][2]);
      acc[mf][3] = MFMA(af[mf], b1, acc[mf][3]);
    }
    __builtin_amdgcn_s_setprio(0);
    if (Tc < NT) VM4(); else VM0();   // RACE FIX: final iter fully drains tile NT-1's loads
    BAR();
    // ---- P3: tile Tb, nf01
#pragma unroll
    for (int mf = 0; mf < 8; ++mf) af[mf] = dsr128(offA(sb, mf));
    b0 = dsr128(offB(sb, 0)); b1 = dsr128(offB(sb, 1));
    if (Td < NT) STG(Aa, aS, Td);
    BAR();
    LGKM0_FENCE();
    __builtin_amdgcn_s_setprio(1);
#pragma unroll
    for (int mf = 0; mf < 8; ++mf) {
      acc[mf][0] = MFMA(af[mf], b0, acc[mf][0]);
      acc[mf][1] = MFMA(af[mf], b1, acc[mf][1]);
    }
    __builtin_amdgcn_s_setprio(0);
    BAR();
    // ---- P4: tile Tb, nf23
    b0 = dsr128(offB(sb, 2)); b1 = dsr128(offB(sb, 3));
    if (Td < NT) STG(Ba, bS, Td);
    BAR();
    LGKM0_FENCE();
    __builtin_amdgcn_s_setprio(1);
#pragma unroll
    for (int mf = 0; mf < 8; ++mf) {
      acc[mf][2] = MFMA(af[mf], b0, acc[mf][2]);
      acc[mf][3] = MFMA(af[mf], b1, acc[mf][3]);
    }
    __builtin_amdgcn_s_setprio(0);
    if (Td < NT) VM4(); else VM0();   // RACE FIX (tail symmetry)
    BAR();
    // rotate slots: next iter (Ta',Tb',Tc') -> (sc, sa, sb)
    const int t = sc; sc = sb; sb = sa; sa = t;
  }
#undef BAR
#undef VM4
#undef VM0
#undef LGKM0_FENCE

#pragma unroll
  for (int mf = 0; mf < 8; ++mf) {
#pragma unroll
    for (int nf = 0; nf < 4; ++nf) {
      const int gr = m0 + wm * 128 + mf * 16 + lc * 4;
      const int gc = n0 + wn * 64 + nf * 16 + lr;
#pragma unroll
      for (int r = 0; r < 4; ++r) {
        float v = acc[mf][nf][r];
        const size_t idx = (size_t)(gr + r) * N + gc;
        if constexpr (MODE == 0) {
          ((u16*)outp)[idx] = f2b(v);
        } else if constexpr (MODE == 1) {
          ((u16*)outp)[idx] = f2b(v + bias[gc]);
        } else if constexpr (MODE == 2) {
          ((float*)outp)[idx] = v + resid[idx];
        } else {
          const float g = b2f(g1[idx]);
          const float sv = v / (1.f + __expf(-v));
          ((u16*)outp)[idx] = f2b(g * sv);
        }
      }
    }
  }
}

// ---------------------------------------------------------------- flash attention (causal), HD=128, KVBLK=64
// K : Ks[k][d] at el = k*128 + (d ^ ((k&7)*8))
// V : Vt[d][k] at el = (d*64 + k) ^ ((d&7)*8)
// P : Ps[w][q][k] at el = q*64 + (k ^ ((q&7)*8))
__global__ __launch_bounds__(256) void attn_kernel(const u16* __restrict__ qkv,
                                                   u16* __restrict__ o, int S) {
  const int qtile = gridDim.x - 1 - blockIdx.x;   // largest-work blocks first
  const int bh = blockIdx.y;
  const int b = bh >> 5, h = bh & 31;
  const int q0 = qtile * 64;
  const int tid = threadIdx.x;
  const int w = tid >> 6, l = tid & 63;
  const int lr = l & 15, lc = l >> 4;
  const size_t RS = 12288;
  const float SCALE = 0.08838834764831845f;  // 128^-0.5

  __shared__ __align__(16) u16 Ks[64 * 128];
  __shared__ __align__(16) u16 Vt[128 * 64];
  __shared__ __align__(16) u16 Ps[4][16 * 64];

  bf16x8 qf[4];
  {
    const u16* qp = qkv + (size_t)(b * S + q0 + w * 16 + lr) * RS + h * 128 + 8 * lc;
#pragma unroll
    for (int kc = 0; kc < 4; ++kc) qf[kc] = *(const bf16x8*)(qp + kc * 32);
  }

  float m_[4], ls[4];
  f32x4 O[8] = {};
#pragma unroll
  for (int r = 0; r < 4; ++r) { m_[r] = -3e38f; ls[r] = 0.f; }

  const int nkt = qtile + 1;
  for (int kt = 0; kt < nkt; ++kt) {
    const int k0 = kt * 64;
#pragma unroll
    for (int it = 0; it < 4; ++it) {
      const int eid = it * 256 + tid;
      const int kr = eid >> 4, d0 = (eid & 15) * 8;
      u16x8 k8 = *(const u16x8*)(qkv + (size_t)(b * S + k0 + kr) * RS + 4096 + h * 128 + d0);
      *(u16x8*)&Ks[kr * 128 + (d0 ^ ((kr & 7) * 8))] = k8;
    }
#pragma unroll
    for (int it = 0; it < 4; ++it) {
      const int d0 = (it * 4 + w) * 8;
      u16x8 v8 = *(const u16x8*)(qkv + (size_t)(b * S + k0 + l) * RS + 8192 + h * 128 + d0);
#pragma unroll
      for (int jj = 0; jj < 8; ++jj) {
        const int d = d0 + jj;
        Vt[(d * 64 + l) ^ ((d & 7) * 8)] = v8[jj];
      }
    }
    __syncthreads();

    const int nks = (kt == qtile) ? (w + 1) : 4;
    float sv[4][4];
#pragma unroll
    for (int ks = 0; ks < 4; ++ks) {
      if (ks < nks) {
        const int row = ks * 16 + lr;
        f32x4 sacc = {0.f, 0.f, 0.f, 0.f};
#pragma unroll
        for (int kc = 0; kc < 4; ++kc) {
          bf16x8 kf = *(const bf16x8*)&Ks[row * 128 + ((kc * 32 + 8 * lc) ^ ((lr & 7) * 8))];
          sacc = MFMA(qf[kc], kf, sacc);
        }
        const bool dm = (kt == qtile) && (ks == w);
#pragma unroll
        for (int r = 0; r < 4; ++r) {
          float x = sacc[r] * SCALE;
          if (dm) {
            const int kg = ks * 16 + lr, qg = w * 16 + lc * 4 + r;
            if (kg > qg) x = -3e38f;
          }
          sv[ks][r] = x;
        }
      } else {
#pragma unroll
        for (int r = 0; r < 4; ++r) sv[ks][r] = -3e38f;
      }
    }

    float alpha[4];
#pragma unroll
    for (int r = 0; r < 4; ++r) {
      float pm = fmaxf(fmaxf(sv[0][r], sv[1][r]), fmaxf(sv[2][r], sv[3][r]));
#pragma unroll
      for (int off = 1; off < 16; off <<= 1) pm = fmaxf(pm, __shfl_xor(pm, off, 64));
      const float mn = fmaxf(m_[r], pm);
      alpha[r] = __expf(m_[r] - mn);
      m_[r] = mn;
    }
    float p[4][4];
#pragma unroll
    for (int ks = 0; ks < 4; ++ks)
#pragma unroll
      for (int r = 0; r < 4; ++r) {
        p[ks][r] = __expf(sv[ks][r] - m_[r]);
        const int q = lc * 4 + r, k = ks * 16 + lr;
        Ps[w][q * 64 + (k ^ ((q & 7) * 8))] = f2b(p[ks][r]);
      }
#pragma unroll
    for (int r = 0; r < 4; ++r) {
      float s = p[0][r] + p[1][r] + p[2][r] + p[3][r];
#pragma unroll
      for (int off = 1; off < 16; off <<= 1) s += __shfl_xor(s, off, 64);
      ls[r] = ls[r] * alpha[r] + s;
    }
#pragma unroll
    for (int dt = 0; dt < 8; ++dt)
#pragma unroll
      for (int r = 0; r < 4; ++r) O[dt][r] *= alpha[r];

#pragma unroll
    for (int half = 0; half < 2; ++half) {
      const bf16x8 ap = *(const bf16x8*)&Ps[w][lr * 64 + ((half * 32 + 8 * lc) ^ ((lr & 7) * 8))];
#pragma unroll
      for (int dt = 0; dt < 8; ++dt) {
        const int d = dt * 16 + lr;
        const bf16x8 bv = *(const bf16x8*)&Vt[d * 64 + ((half * 32 + 8 * lc) ^ ((d & 7) * 8))];
        O[dt] = MFMA(ap, bv, O[dt]);
      }
    }
    __syncthreads();
  }

  float inv[4];
#pragma unroll
  for (int r = 0; r < 4; ++r) inv[r] = 1.f / ls[r];
#pragma unroll
  for (int dt = 0; dt < 8; ++dt)
#pragma unroll
    for (int r = 0; r < 4; ++r) {
      const int qg = q0 + w * 16 + lc * 4 + r;
      o[(size_t)(b * S + qg) * 4096 + h * 128 + dt * 16 + lr] = f2b(O[dt][r] * inv[r]);
    }
}

// ---------------------------------------------------------------- launch
extern "C" void kernel_launch(void* const* d_in, const int* in_sizes, int n_in,
                              void* d_out, int out_size, void* d_ws, size_t ws_size,
                              hipStream_t stream) {
  const int*   positions = (const int*)d_in[0];
  const float* hidden    = (const float*)d_in[1];
  const float* ln1       = (const float*)d_in[2];
  const float* ln2       = (const float*)d_in[3];
  const float* Wqkv      = (const float*)d_in[4];
  const float* bqkv      = (const float*)d_in[5];
  const float* Wo        = (const float*)d_in[6];
  const float* W1        = (const float*)d_in[7];
  const float* W2        = (const float*)d_in[8];
  const float* Wout      = (const float*)d_in[9];
  float* out = (float*)d_out;

  const int S = 2048, BS = 4096, D = 4096, FF = 11008, N3 = 12288;

  char* ws = (char*)d_ws;
  size_t off = 0;
  auto alloc = [&](size_t bytes) { void* p = ws + off; off += (bytes + 255) & ~(size_t)255; return p; };
  u16*   WT    = (u16*)alloc((size_t)N3 * D * 2);       // reused for every weight
  u16*   qkv   = (u16*)alloc((size_t)BS * N3 * 2);
  u16*   slotH = (u16*)alloc((size_t)BS * D * 2);       // h / attn_out / h3
  float* h2    = (float*)alloc((size_t)BS * D * 4);
  u16*   slotG = (u16*)alloc((size_t)BS * FF * 2);      // G1 -> act in-place
  float* tab   = (float*)alloc((size_t)2 * BS * 64 * 4);
  if (ws_size < off) return;

  rope_table<<<(BS * 64 + 255) / 256, 256, 0, stream>>>(positions, tab, BS);

  // h = rmsnorm(hidden) ; qkv = h @ Wqkv + b
  transpose_cvt<<<dim3(N3 / 64, D / 64), dim3(64, 4), 0, stream>>>(Wqkv, WT, D, N3);
  rmsnorm_k<<<BS, 256, 0, stream>>>(hidden, ln1, slotH, D);
  gemm256<1><<<dim3(N3 / 256, BS / 256), 512, 0, stream>>>(slotH, WT, qkv, bqkv, nullptr, nullptr, BS, N3, D);
  rope_apply<<<(BS * 1024) / 256, 256, 0, stream>>>(qkv, tab, BS);

  // attention (64 q-rows per block, 4 waves — r16 verified)
  attn_kernel<<<dim3(S / 64, 64), 256, 0, stream>>>(qkv, slotH, S);

  // h2 = hidden + attn @ Wo
  transpose_cvt<<<dim3(D / 64, D / 64), dim3(64, 4), 0, stream>>>(Wo, WT, D, D);
  gemm256<2><<<dim3(D / 256, BS / 256), 512, 0, stream>>>(slotH, WT, h2, nullptr, hidden, nullptr, BS, D, D);

  // h3 = rmsnorm(h2) ; G1 = h3@W1 ; act = G1 * silu(h3@W2) ; out = h2 + act@Wout
  rmsnorm_k<<<BS, 256, 0, stream>>>(h2, ln2, slotH, D);
  transpose_cvt<<<dim3(FF / 64, D / 64), dim3(64, 4), 0, stream>>>(W1, WT, D, FF);
  gemm256<0><<<dim3(FF / 256, BS / 256), 512, 0, stream>>>(slotH, WT, slotG, nullptr, nullptr, nullptr, BS, FF, D);
  transpose_cvt<<<dim3(FF / 64, D / 64), dim3(64, 4), 0, stream>>>(W2, WT, D, FF);
  gemm256<3><<<dim3(FF / 256, BS / 256), 512, 0, stream>>>(slotH, WT, slotG, nullptr, nullptr, slotG, BS, FF, D);
  transpose_cvt<<<dim3(D / 64, FF / 64), dim3(64, 4), 0, stream>>>(Wout, WT, FF, D);
  gemm256<2><<<dim3(D / 256, BS / 256), 512, 0, stream>>>(slotG, WT, out, nullptr, h2, nullptr, BS, D, FF);
}

// Round 19
// 2243.166 us; speedup vs baseline: 1.0271x; 1.0193x over previous
//
#include <hip/hip_runtime.h>

typedef unsigned short u16;
typedef unsigned int   u32;
typedef __bf16 bf16x8 __attribute__((ext_vector_type(8)));
typedef float  f32x4  __attribute__((ext_vector_type(4)));
typedef unsigned short u16x2 __attribute__((ext_vector_type(2)));
typedef unsigned short u16x4 __attribute__((ext_vector_type(4)));
typedef unsigned short u16x8 __attribute__((ext_vector_type(8)));
typedef unsigned int   u32x4 __attribute__((ext_vector_type(4)));

#define DEV __device__ __forceinline__

DEV u16 f2b(float f) {                      // f32 -> bf16 RNE
  u32 u = __builtin_bit_cast(u32, f);
  return (u16)((u + 0x7fffu + ((u >> 16) & 1u)) >> 16);
}
DEV float b2f(u16 h) { u32 u = ((u32)h) << 16; return __builtin_bit_cast(float, u); }

DEV void gload16(const void* g, void* l) {  // async global->LDS, 16B/lane
  __builtin_amdgcn_global_load_lds((__attribute__((address_space(1))) void*)(g),
                                   (__attribute__((address_space(3))) void*)(l),
                                   16, 0, 0);
}

DEV f32x4 MFMA(bf16x8 a, bf16x8 b, f32x4 c) {
  return __builtin_amdgcn_mfma_f32_16x16x32_bf16(a, b, c, 0, 0, 0);
}

DEV u32 ldsoff(const void* p) {             // LDS byte offset for ds_* asm
  return (u32)(uintptr_t)(__attribute__((address_space(3))) void*)p;
}
DEV bf16x8 dsr128(u32 a) {                  // compiler-opaque LDS read
  u32x4 d;
  asm volatile("ds_read_b128 %0, %1" : "=v"(d) : "v"(a) : "memory");
  return __builtin_bit_cast(bf16x8, d);
}

// ---------------------------------------------------------------- transpose+cvt (64x64 tiles, vectorized)
__global__ __launch_bounds__(256) void transpose_cvt(const float* __restrict__ W,
                                                     u16* __restrict__ Wt,
                                                     int K, int N) {
  __shared__ float tile[64][65];
  const int n0 = blockIdx.x * 64, k0 = blockIdx.y * 64;
  const int tx = threadIdx.x, ty = threadIdx.y;  // 64 x 4
#pragma unroll
  for (int i = 0; i < 16; ++i) {
    const int row = ty + i * 4;
    tile[row][tx] = W[(size_t)(k0 + row) * N + n0 + tx];
  }
  __syncthreads();
#pragma unroll
  for (int i = 0; i < 8; ++i) {
    const int nrow = ty * 2 + (tx >> 5) + i * 8;
    const int kp = (tx & 31) * 2;
    u16x2 v;
    v[0] = f2b(tile[kp][nrow]);
    v[1] = f2b(tile[kp + 1][nrow]);
    *(u16x2*)&Wt[(size_t)(n0 + nrow) * K + k0 + kp] = v;
  }
}

// ---------------------------------------------------------------- rmsnorm (f32 in, bf16 out), D=4096
__global__ __launch_bounds__(256) void rmsnorm_k(const float* __restrict__ x,
                                                 const float* __restrict__ w,
                                                 u16* __restrict__ o, int D) {
  const int row = blockIdx.x, tid = threadIdx.x;
  const float4* xr = (const float4*)(x + (size_t)row * D);
  const float4* wr = (const float4*)w;
  float4 v[4];
  float ss = 0.f;
#pragma unroll
  for (int i = 0; i < 4; ++i) {
    v[i] = xr[i * 256 + tid];
    ss += v[i].x * v[i].x + v[i].y * v[i].y + v[i].z * v[i].z + v[i].w * v[i].w;
  }
#pragma unroll
  for (int off = 1; off < 64; off <<= 1) ss += __shfl_xor(ss, off, 64);
  __shared__ float red[4];
  if ((tid & 63) == 0) red[tid >> 6] = ss;
  __syncthreads();
  const float tot = red[0] + red[1] + red[2] + red[3];
  const float sc = rsqrtf(tot / (float)D + 1e-6f);
  u16x4* orow = (u16x4*)(o + (size_t)row * D);
#pragma unroll
  for (int i = 0; i < 4; ++i) {
    float4 wv = wr[i * 256 + tid];
    u16x4 p;
    p[0] = f2b(v[i].x * sc * wv.x);
    p[1] = f2b(v[i].y * sc * wv.y);
    p[2] = f2b(v[i].z * sc * wv.z);
    p[3] = f2b(v[i].w * sc * wv.w);
    orow[i * 256 + tid] = p;
  }
}

// ---------------------------------------------------------------- RoPE table
__global__ __launch_bounds__(256) void rope_table(const int* __restrict__ positions,
                                                  float* __restrict__ tab, int BS) {
  const int idx = blockIdx.x * 256 + threadIdx.x;
  if (idx >= BS * 64) return;
  const int bs = idx >> 6, i = idx & 63;
  const float pos = (float)positions[bs];
  const float inv = __expf(-(float)i * (9.210340371976184f / 64.f));
  const float ang = pos * inv;
  float s, c;
  sincosf(ang, &s, &c);
  tab[idx] = c;
  tab[BS * 64 + idx] = s;
}

// ---------------------------------------------------------------- RoPE in-place on bf16 qkv [BS][12288], u16x2-vectorized
__global__ __launch_bounds__(256) void rope_apply(u16* __restrict__ qkv,
                                                  const float* __restrict__ tab, int BS) {
  const int idx = blockIdx.x * 256 + threadIdx.x;  // (bs, h, i-pair)
  if (idx >= BS * 1024) return;
  const int ip = (idx & 31) * 2, h = (idx >> 5) & 31, bs = idx >> 10;
  const float2 c2 = ((const float2*)tab)[bs * 32 + (ip >> 1)];
  const float2 s2 = ((const float2*)(tab + (size_t)BS * 64))[bs * 32 + (ip >> 1)];
  const size_t base = (size_t)bs * 12288 + h * 128 + ip;
  u16x2 a1 = *(const u16x2*)&qkv[base];
  u16x2 a2 = *(const u16x2*)&qkv[base + 64];
  u16x2 b1 = *(const u16x2*)&qkv[base + 4096];
  u16x2 b2 = *(const u16x2*)&qkv[base + 4096 + 64];
  u16x2 r;
  r[0] = f2b(b2f(a1[0]) * c2.x - b2f(a2[0]) * s2.x);
  r[1] = f2b(b2f(a1[1]) * c2.y - b2f(a2[1]) * s2.y);
  *(u16x2*)&qkv[base] = r;
  r[0] = f2b(b2f(a2[0]) * c2.x + b2f(a1[0]) * s2.x);
  r[1] = f2b(b2f(a2[1]) * c2.y + b2f(a1[1]) * s2.y);
  *(u16x2*)&qkv[base + 64] = r;
  r[0] = f2b(b2f(b1[0]) * c2.x - b2f(b2[0]) * s2.x);
  r[1] = f2b(b2f(b1[1]) * c2.y - b2f(b2[1]) * s2.y);
  *(u16x2*)&qkv[base + 4096] = r;
  r[0] = f2b(b2f(b2[0]) * c2.x + b2f(b1[0]) * s2.x);
  r[1] = f2b(b2f(b2[1]) * c2.y + b2f(b1[1]) * s2.y);
  *(u16x2*)&qkv[base + 4096 + 64] = r;
}

// ---------------------------------------------------------------- GEMM 256x256, BK=32, 8 waves, 4-phase (m201 template)
// Replay-verified (r15/r16/r18): 3-slot ring, chunk swizzle pos = c ^ ((r>>1)&3) (0 conflicts),
// inline-asm ds_read_b128 + rule-18 fence, counted vmcnt(4) with FINAL-ITERATION vmcnt(0) race fix,
// setprio around MFMA, T1 XCD swizzle.
// MODE 0: bf16 out   1: bf16 + f32 bias[col]   2: f32 + f32 resid
template <int MODE>
__global__ __launch_bounds__(512, 2) void gemm256(const u16* __restrict__ A,
                                                  const u16* __restrict__ Bt,
                                                  void* __restrict__ outp,
                                                  const float* __restrict__ bias,
                                                  const float* __restrict__ resid,
                                                  int M, int N, int K) {
  __shared__ __align__(16) u16 As[3 * 8192];
  __shared__ __align__(16) u16 Bs[3 * 8192];     // 96 KiB total
  const int tid = threadIdx.x;
  const int wid = tid >> 6, l = tid & 63;
  const int wm = wid >> 2, wn = wid & 3;          // 2 x 4 waves, each owns 128x64
  const int lr = l & 15, lc = l >> 4;
  const int gx = gridDim.x;
  const int nwg = gx * gridDim.y;
  const int orig = blockIdx.y * gx + blockIdx.x;
  const int wg = (orig & 7) * (nwg >> 3) + (orig >> 3);
  const int m0 = (wg / gx) * 256, n0 = (wg % gx) * 256;

  const int NT = K >> 5;
  const int NI = NT >> 1;

  const int rt = tid >> 2;
  const int ct = (tid & 3) ^ ((rt >> 1) & 3);
  const u16* aS = A + (size_t)(m0 + rt) * K + ct * 8;
  const u16* bS = Bt + (size_t)(n0 + rt) * K + ct * 8;

  auto STG = [&](u16* slot, const u16* src, int tk) {
    gload16(src + tk * 32, slot + wid * 512);
    gload16(src + (size_t)128 * K + tk * 32, slot + 4096 + wid * 512);
  };

  const u32 aBase = ldsoff(As), bBase = ldsoff(Bs);
  auto offA = [&](int slot, int mf) {
    const int r = wm * 128 + mf * 16 + lr;
    return aBase + (u32)slot * 16384u + (u32)(r * 64 + ((lc ^ ((r >> 1) & 3)) * 16));
  };
  auto offB = [&](int slot, int nf) {
    const int r = wn * 64 + nf * 16 + lr;
    return bBase + (u32)slot * 16384u + (u32)(r * 64 + ((lc ^ ((r >> 1) & 3)) * 16));
  };

  f32x4 acc[8][4] = {};

#define BAR()  asm volatile("s_barrier" ::: "memory")
#define VM4()  asm volatile("s_waitcnt vmcnt(4)" ::: "memory")
#define VM0()  asm volatile("s_waitcnt vmcnt(0)" ::: "memory")
#define LGKM0_FENCE() do { asm volatile("s_waitcnt lgkmcnt(0)" ::: "memory"); \
                           __builtin_amdgcn_sched_barrier(0); } while (0)

  STG(&As[0], aS, 0);
  STG(&Bs[0], bS, 0);
  STG(&As[8192], aS, 1);
  STG(&Bs[8192], bS, 1);
  VM4();
  BAR();

  int sa = 0, sb = 1, sc = 2;
  for (int i = 0; i < NI; ++i) {
    const int Tc = 2 * i + 2, Td = 2 * i + 3;
    u16* Aa = &As[sa * 8192]; u16* Ba = &Bs[sa * 8192];
    u16* Ac = &As[sc * 8192]; u16* Bc = &Bs[sc * 8192];
    bf16x8 af[8], b0, b1;
    // ---- P1
#pragma unroll
    for (int mf = 0; mf < 8; ++mf) af[mf] = dsr128(offA(sa, mf));
    b0 = dsr128(offB(sa, 0)); b1 = dsr128(offB(sa, 1));
    if (Tc < NT) STG(Ac, aS, Tc);
    BAR();
    LGKM0_FENCE();
    __builtin_amdgcn_s_setprio(1);
#pragma unroll
    for (int mf = 0; mf < 8; ++mf) {
      acc[mf][0] = MFMA(af[mf], b0, acc[mf][0]);
      acc[mf][1] = MFMA(af[mf], b1, acc[mf][1]);
    }
    __builtin_amdgcn_s_setprio(0);
    BAR();
    // ---- P2
    b0 = dsr128(offB(sa, 2)); b1 = dsr128(offB(sa, 3));
    if (Tc < NT) STG(Bc, bS, Tc);
    BAR();
    LGKM0_FENCE();
    __builtin_amdgcn_s_setprio(1);
#pragma unroll
    for (int mf = 0; mf < 8; ++mf) {
      acc[mf][2] = MFMA(af[mf], b0, acc[mf][2]);
      acc[mf][3] = MFMA(af[mf], b1, acc[mf][3]);
    }
    __builtin_amdgcn_s_setprio(0);
    if (Tc < NT) VM4(); else VM0();   // RACE FIX
    BAR();
    // ---- P3
#pragma unroll
    for (int mf = 0; mf < 8; ++mf) af[mf] = dsr128(offA(sb, mf));
    b0 = dsr128(offB(sb, 0)); b1 = dsr128(offB(sb, 1));
    if (Td < NT) STG(Aa, aS, Td);
    BAR();
    LGKM0_FENCE();
    __builtin_amdgcn_s_setprio(1);
#pragma unroll
    for (int mf = 0; mf < 8; ++mf) {
      acc[mf][0] = MFMA(af[mf], b0, acc[mf][0]);
      acc[mf][1] = MFMA(af[mf], b1, acc[mf][1]);
    }
    __builtin_amdgcn_s_setprio(0);
    BAR();
    // ---- P4
    b0 = dsr128(offB(sb, 2)); b1 = dsr128(offB(sb, 3));
    if (Td < NT) STG(Ba, bS, Td);
    BAR();
    LGKM0_FENCE();
    __builtin_amdgcn_s_setprio(1);
#pragma unroll
    for (int mf = 0; mf < 8; ++mf) {
      acc[mf][2] = MFMA(af[mf], b0, acc[mf][2]);
      acc[mf][3] = MFMA(af[mf], b1, acc[mf][3]);
    }
    __builtin_amdgcn_s_setprio(0);
    if (Td < NT) VM4(); else VM0();   // RACE FIX
    BAR();
    const int t = sc; sc = sb; sb = sa; sa = t;
  }
#undef BAR
#undef VM4
#undef VM0
#undef LGKM0_FENCE

#pragma unroll
  for (int mf = 0; mf < 8; ++mf) {
#pragma unroll
    for (int nf = 0; nf < 4; ++nf) {
      const int gr = m0 + wm * 128 + mf * 16 + lc * 4;
      const int gc = n0 + wn * 64 + nf * 16 + lr;
#pragma unroll
      for (int r = 0; r < 4; ++r) {
        float v = acc[mf][nf][r];
        const size_t idx = (size_t)(gr + r) * N + gc;
        if constexpr (MODE == 0) {
          ((u16*)outp)[idx] = f2b(v);
        } else if constexpr (MODE == 1) {
          ((u16*)outp)[idx] = f2b(v + bias[gc]);
        } else {
          ((float*)outp)[idx] = v + resid[idx];
        }
      }
    }
  }
}

// ---------------------------------------------------------------- FUSED SwiGLU GEMM: act = (A@W1t^T) * silu(A@W2t^T)
// Same verified 4-phase schedule/LDS/swizzle as gemm256. Each block computes matching 256x128 tiles of
// G1 and G2: Bs rows 0..127 <- W1t rows n0..n0+127, rows 128..255 <- W2t rows n0..n0+127 (same rt/ct
// involution: (128+rt)>>1 & 3 == (rt>>1)&3 since 128 % 4 == 0). Per wave: nf 0,1 = W1 cols, nf 2,3 = W2
// cols at the SAME columns; epilogue multiplies in registers -> no G1 buffer traffic at all.
__global__ __launch_bounds__(512, 2) void gemm_swiglu(const u16* __restrict__ A,
                                                      const u16* __restrict__ W1t,
                                                      const u16* __restrict__ W2t,
                                                      u16* __restrict__ outp,
                                                      int M, int N, int K) {
  __shared__ __align__(16) u16 As[3 * 8192];
  __shared__ __align__(16) u16 Bs[3 * 8192];
  const int tid = threadIdx.x;
  const int wid = tid >> 6, l = tid & 63;
  const int wm = wid >> 2, wn = wid & 3;          // 2 x 4 waves; wave owns 128 rows x 32 cols (of both G1,G2)
  const int lr = l & 15, lc = l >> 4;
  const int gx = gridDim.x;                       // N/128 blocks in x
  const int nwg = gx * gridDim.y;                 // nwg % 8 == 0
  const int orig = blockIdx.y * gx + blockIdx.x;
  const int wg = (orig & 7) * (nwg >> 3) + (orig >> 3);
  const int m0 = (wg / gx) * 256, n0 = (wg % gx) * 128;

  const int NT = K >> 5;
  const int NI = NT >> 1;

  const int rt = tid >> 2;
  const int ct = (tid & 3) ^ ((rt >> 1) & 3);
  const u16* aS  = A   + (size_t)(m0 + rt) * K + ct * 8;
  const u16* b1S = W1t + (size_t)(n0 + rt) * K + ct * 8;
  const u16* b2S = W2t + (size_t)(n0 + rt) * K + ct * 8;

  auto STGA = [&](u16* slot, int tk) {
    gload16(aS + tk * 32, slot + wid * 512);
    gload16(aS + (size_t)128 * K + tk * 32, slot + 4096 + wid * 512);
  };
  auto STGB = [&](u16* slot, int tk) {            // rows 0..127 <- W1t, rows 128..255 <- W2t
    gload16(b1S + tk * 32, slot + wid * 512);
    gload16(b2S + tk * 32, slot + 4096 + wid * 512);
  };

  const u32 aBase = ldsoff(As), bBase = ldsoff(Bs);
  auto offA = [&](int slot, int mf) {
    const int r = wm * 128 + mf * 16 + lr;
    return aBase + (u32)slot * 16384u + (u32)(r * 64 + ((lc ^ ((r >> 1) & 3)) * 16));
  };
  auto offB = [&](int slot, int nf) {             // nf 0,1 -> W1 half; nf 2,3 -> W2 half, same cols
    const int r = (nf < 2) ? (wn * 32 + nf * 16 + lr) : (128 + wn * 32 + (nf - 2) * 16 + lr);
    return bBase + (u32)slot * 16384u + (u32)(r * 64 + ((lc ^ ((r >> 1) & 3)) * 16));
  };

  f32x4 acc[8][4] = {};

#define BAR()  asm volatile("s_barrier" ::: "memory")
#define VM4()  asm volatile("s_waitcnt vmcnt(4)" ::: "memory")
#define VM0()  asm volatile("s_waitcnt vmcnt(0)" ::: "memory")
#define LGKM0_FENCE() do { asm volatile("s_waitcnt lgkmcnt(0)" ::: "memory"); \
                           __builtin_amdgcn_sched_barrier(0); } while (0)

  STGA(&As[0], 0);
  STGB(&Bs[0], 0);
  STGA(&As[8192], 1);
  STGB(&Bs[8192], 1);
  VM4();
  BAR();

  int sa = 0, sb = 1, sc = 2;
  for (int i = 0; i < NI; ++i) {
    const int Tc = 2 * i + 2, Td = 2 * i + 3;
    u16* Aa = &As[sa * 8192]; u16* Ba = &Bs[sa * 8192];
    u16* Ac = &As[sc * 8192]; u16* Bc = &Bs[sc * 8192];
    bf16x8 af[8], b0, b1;
    // ---- P1
#pragma unroll
    for (int mf = 0; mf < 8; ++mf) af[mf] = dsr128(offA(sa, mf));
    b0 = dsr128(offB(sa, 0)); b1 = dsr128(offB(sa, 1));
    if (Tc < NT) STGA(Ac, Tc);
    BAR();
    LGKM0_FENCE();
    __builtin_amdgcn_s_setprio(1);
#pragma unroll
    for (int mf = 0; mf < 8; ++mf) {
      acc[mf][0] = MFMA(af[mf], b0, acc[mf][0]);
      acc[mf][1] = MFMA(af[mf], b1, acc[mf][1]);
    }
    __builtin_amdgcn_s_setprio(0);
    BAR();
    // ---- P2
    b0 = dsr128(offB(sa, 2)); b1 = dsr128(offB(sa, 3));
    if (Tc < NT) STGB(Bc, Tc);
    BAR();
    LGKM0_FENCE();
    __builtin_amdgcn_s_setprio(1);
#pragma unroll
    for (int mf = 0; mf < 8; ++mf) {
      acc[mf][2] = MFMA(af[mf], b0, acc[mf][2]);
      acc[mf][3] = MFMA(af[mf], b1, acc[mf][3]);
    }
    __builtin_amdgcn_s_setprio(0);
    if (Tc < NT) VM4(); else VM0();   // RACE FIX (verified r15)
    BAR();
    // ---- P3
#pragma unroll
    for (int mf = 0; mf < 8; ++mf) af[mf] = dsr128(offA(sb, mf));
    b0 = dsr128(offB(sb, 0)); b1 = dsr128(offB(sb, 1));
    if (Td < NT) STGA(Aa, Td);
    BAR();
    LGKM0_FENCE();
    __builtin_amdgcn_s_setprio(1);
#pragma unroll
    for (int mf = 0; mf < 8; ++mf) {
      acc[mf][0] = MFMA(af[mf], b0, acc[mf][0]);
      acc[mf][1] = MFMA(af[mf], b1, acc[mf][1]);
    }
    __builtin_amdgcn_s_setprio(0);
    BAR();
    // ---- P4
    b0 = dsr128(offB(sb, 2)); b1 = dsr128(offB(sb, 3));
    if (Td < NT) STGB(Ba, Td);
    BAR();
    LGKM0_FENCE();
    __builtin_amdgcn_s_setprio(1);
#pragma unroll
    for (int mf = 0; mf < 8; ++mf) {
      acc[mf][2] = MFMA(af[mf], b0, acc[mf][2]);
      acc[mf][3] = MFMA(af[mf], b1, acc[mf][3]);
    }
    __builtin_amdgcn_s_setprio(0);
    if (Td < NT) VM4(); else VM0();   // RACE FIX
    BAR();
    const int t = sc; sc = sb; sb = sa; sa = t;
  }
#undef BAR
#undef VM4
#undef VM0
#undef LGKM0_FENCE

  // epilogue: act = g1 * silu(g2), both in registers (nf and nf+2 hold same columns)
#pragma unroll
  for (int mf = 0; mf < 8; ++mf) {
#pragma unroll
    for (int nf = 0; nf < 2; ++nf) {
      const int gr = m0 + wm * 128 + mf * 16 + lc * 4;
      const int gc = n0 + wn * 32 + nf * 16 + lr;
#pragma unroll
      for (int r = 0; r < 4; ++r) {
        const float g1 = acc[mf][nf][r];
        const float g2 = acc[mf][nf + 2][r];
        const float sv = g2 / (1.f + __expf(-g2));
        outp[(size_t)(gr + r) * N + gc] = f2b(g1 * sv);
      }
    }
  }
}

// ---------------------------------------------------------------- flash attention (causal), HD=128, KVBLK=64
// K : Ks[k][d] at el = k*128 + (d ^ ((k&7)*8))
// V : Vt[d][k] at el = (d*64 + k) ^ ((d&7)*8)
// P : Ps[w][q][k] at el = q*64 + (k ^ ((q&7)*8))
__global__ __launch_bounds__(256) void attn_kernel(const u16* __restrict__ qkv,
                                                   u16* __restrict__ o, int S) {
  const int qtile = gridDim.x - 1 - blockIdx.x;   // largest-work blocks first
  const int bh = blockIdx.y;
  const int b = bh >> 5, h = bh & 31;
  const int q0 = qtile * 64;
  const int tid = threadIdx.x;
  const int w = tid >> 6, l = tid & 63;
  const int lr = l & 15, lc = l >> 4;
  const size_t RS = 12288;
  const float SCALE = 0.08838834764831845f;  // 128^-0.5

  __shared__ __align__(16) u16 Ks[64 * 128];
  __shared__ __align__(16) u16 Vt[128 * 64];
  __shared__ __align__(16) u16 Ps[4][16 * 64];

  bf16x8 qf[4];
  {
    const u16* qp = qkv + (size_t)(b * S + q0 + w * 16 + lr) * RS + h * 128 + 8 * lc;
#pragma unroll
    for (int kc = 0; kc < 4; ++kc) qf[kc] = *(const bf16x8*)(qp + kc * 32);
  }

  float m_[4], ls[4];
  f32x4 O[8] = {};
#pragma unroll
  for (int r = 0; r < 4; ++r) { m_[r] = -3e38f; ls[r] = 0.f; }

  const int nkt = qtile + 1;
  for (int kt = 0; kt < nkt; ++kt) {
    const int k0 = kt * 64;
#pragma unroll
    for (int it = 0; it < 4; ++it) {
      const int eid = it * 256 + tid;
      const int kr = eid >> 4, d0 = (eid & 15) * 8;
      u16x8 k8 = *(const u16x8*)(qkv + (size_t)(b * S + k0 + kr) * RS + 4096 + h * 128 + d0);
      *(u16x8*)&Ks[kr * 128 + (d0 ^ ((kr & 7) * 8))] = k8;
    }
#pragma unroll
    for (int it = 0; it < 4; ++it) {
      const int d0 = (it * 4 + w) * 8;
      u16x8 v8 = *(const u16x8*)(qkv + (size_t)(b * S + k0 + l) * RS + 8192 + h * 128 + d0);
#pragma unroll
      for (int jj = 0; jj < 8; ++jj) {
        const int d = d0 + jj;
        Vt[(d * 64 + l) ^ ((d & 7) * 8)] = v8[jj];
      }
    }
    __syncthreads();

    const int nks = (kt == qtile) ? (w + 1) : 4;
    float sv[4][4];
#pragma unroll
    for (int ks = 0; ks < 4; ++ks) {
      if (ks < nks) {
        const int row = ks * 16 + lr;
        f32x4 sacc = {0.f, 0.f, 0.f, 0.f};
#pragma unroll
        for (int kc = 0; kc < 4; ++kc) {
          bf16x8 kf = *(const bf16x8*)&Ks[row * 128 + ((kc * 32 + 8 * lc) ^ ((lr & 7) * 8))];
          sacc = MFMA(qf[kc], kf, sacc);
        }
        const bool dm = (kt == qtile) && (ks == w);
#pragma unroll
        for (int r = 0; r < 4; ++r) {
          float x = sacc[r] * SCALE;
          if (dm) {
            const int kg = ks * 16 + lr, qg = w * 16 + lc * 4 + r;
            if (kg > qg) x = -3e38f;
          }
          sv[ks][r] = x;
        }
      } else {
#pragma unroll
        for (int r = 0; r < 4; ++r) sv[ks][r] = -3e38f;
      }
    }

    float alpha[4];
#pragma unroll
    for (int r = 0; r < 4; ++r) {
      float pm = fmaxf(fmaxf(sv[0][r], sv[1][r]), fmaxf(sv[2][r], sv[3][r]));
#pragma unroll
      for (int off = 1; off < 16; off <<= 1) pm = fmaxf(pm, __shfl_xor(pm, off, 64));
      const float mn = fmaxf(m_[r], pm);
      alpha[r] = __expf(m_[r] - mn);
      m_[r] = mn;
    }
    float p[4][4];
#pragma unroll
    for (int ks = 0; ks < 4; ++ks)
#pragma unroll
      for (int r = 0; r < 4; ++r) {
        p[ks][r] = __expf(sv[ks][r] - m_[r]);
        const int q = lc * 4 + r, k = ks * 16 + lr;
        Ps[w][q * 64 + (k ^ ((q & 7) * 8))] = f2b(p[ks][r]);
      }
#pragma unroll
    for (int r = 0; r < 4; ++r) {
      float s = p[0][r] + p[1][r] + p[2][r] + p[3][r];
#pragma unroll
      for (int off = 1; off < 16; off <<= 1) s += __shfl_xor(s, off, 64);
      ls[r] = ls[r] * alpha[r] + s;
    }
#pragma unroll
    for (int dt = 0; dt < 8; ++dt)
#pragma unroll
      for (int r = 0; r < 4; ++r) O[dt][r] *= alpha[r];

#pragma unroll
    for (int half = 0; half < 2; ++half) {
      const bf16x8 ap = *(const bf16x8*)&Ps[w][lr * 64 + ((half * 32 + 8 * lc) ^ ((lr & 7) * 8))];
#pragma unroll
      for (int dt = 0; dt < 8; ++dt) {
        const int d = dt * 16 + lr;
        const bf16x8 bv = *(const bf16x8*)&Vt[d * 64 + ((half * 32 + 8 * lc) ^ ((d & 7) * 8))];
        O[dt] = MFMA(ap, bv, O[dt]);
      }
    }
    __syncthreads();
  }

  float inv[4];
#pragma unroll
  for (int r = 0; r < 4; ++r) inv[r] = 1.f / ls[r];
#pragma unroll
  for (int dt = 0; dt < 8; ++dt)
#pragma unroll
    for (int r = 0; r < 4; ++r) {
      const int qg = q0 + w * 16 + lc * 4 + r;
      o[(size_t)(b * S + qg) * 4096 + h * 128 + dt * 16 + lr] = f2b(O[dt][r] * inv[r]);
    }
}

// ---------------------------------------------------------------- launch
extern "C" void kernel_launch(void* const* d_in, const int* in_sizes, int n_in,
                              void* d_out, int out_size, void* d_ws, size_t ws_size,
                              hipStream_t stream) {
  const int*   positions = (const int*)d_in[0];
  const float* hidden    = (const float*)d_in[1];
  const float* ln1       = (const float*)d_in[2];
  const float* ln2       = (const float*)d_in[3];
  const float* Wqkv      = (const float*)d_in[4];
  const float* bqkv      = (const float*)d_in[5];
  const float* Wo        = (const float*)d_in[6];
  const float* W1        = (const float*)d_in[7];
  const float* W2        = (const float*)d_in[8];
  const float* Wout      = (const float*)d_in[9];
  float* out = (float*)d_out;

  const int S = 2048, BS = 4096, D = 4096, FF = 11008, N3 = 12288;

  char* ws = (char*)d_ws;
  size_t off = 0;
  auto alloc = [&](size_t bytes) { void* p = ws + off; off += (bytes + 255) & ~(size_t)255; return p; };
  u16*   WT    = (u16*)alloc((size_t)N3 * D * 2);       // reused for every weight
  u16*   qkv   = (u16*)alloc((size_t)BS * N3 * 2);      // qkv; later reused as W2t (dead after attn)
  u16*   slotH = (u16*)alloc((size_t)BS * D * 2);       // h / attn_out / h3
  float* h2    = (float*)alloc((size_t)BS * D * 4);
  u16*   slotG = (u16*)alloc((size_t)BS * FF * 2);      // act
  float* tab   = (float*)alloc((size_t)2 * BS * 64 * 4);
  if (ws_size < off) return;

  rope_table<<<(BS * 64 + 255) / 256, 256, 0, stream>>>(positions, tab, BS);

  // h = rmsnorm(hidden) ; qkv = h @ Wqkv + b
  transpose_cvt<<<dim3(N3 / 64, D / 64), dim3(64, 4), 0, stream>>>(Wqkv, WT, D, N3);
  rmsnorm_k<<<BS, 256, 0, stream>>>(hidden, ln1, slotH, D);
  gemm256<1><<<dim3(N3 / 256, BS / 256), 512, 0, stream>>>(slotH, WT, qkv, bqkv, nullptr, BS, N3, D);
  rope_apply<<<(BS * 1024) / 256, 256, 0, stream>>>(qkv, tab, BS);

  // attention (64 q-rows per block, 4 waves — r16/r18 verified)
  attn_kernel<<<dim3(S / 64, 64), 256, 0, stream>>>(qkv, slotH, S);

  // h2 = hidden + attn @ Wo
  transpose_cvt<<<dim3(D / 64, D / 64), dim3(64, 4), 0, stream>>>(Wo, WT, D, D);
  gemm256<2><<<dim3(D / 256, BS / 256), 512, 0, stream>>>(slotH, WT, h2, nullptr, hidden, BS, D, D);

  // h3 = rmsnorm(h2) ; act = (h3@W1) * silu(h3@W2) fused ; out = h2 + act@Wout
  rmsnorm_k<<<BS, 256, 0, stream>>>(h2, ln2, slotH, D);
  transpose_cvt<<<dim3(FF / 64, D / 64), dim3(64, 4), 0, stream>>>(W1, WT, D, FF);
  transpose_cvt<<<dim3(FF / 64, D / 64), dim3(64, 4), 0, stream>>>(W2, qkv, D, FF);  // qkv buffer = W2t
  gemm_swiglu<<<dim3(FF / 128, BS / 256), 512, 0, stream>>>(slotH, WT, qkv, slotG, BS, FF, D);
  transpose_cvt<<<dim3(D / 64, FF / 64), dim3(64, 4), 0, stream>>>(Wout, WT, FF, D);
  gemm256<2><<<dim3(D / 256, BS / 256), 512, 0, stream>>>(slotG, WT, out, nullptr, h2, BS, D, FF);
}

// Round 20
// 2232.787 us; speedup vs baseline: 1.0319x; 1.0046x over previous
//
#include <hip/hip_runtime.h>

typedef unsigned short u16;
typedef unsigned int   u32;
typedef __bf16 bf16x8 __attribute__((ext_vector_type(8)));
typedef float  f32x4  __attribute__((ext_vector_type(4)));
typedef unsigned short u16x2 __attribute__((ext_vector_type(2)));
typedef unsigned short u16x4 __attribute__((ext_vector_type(4)));
typedef unsigned short u16x8 __attribute__((ext_vector_type(8)));
typedef unsigned int   u32x4 __attribute__((ext_vector_type(4)));

#define DEV __device__ __forceinline__

DEV u16 f2b(float f) {                      // f32 -> bf16 RNE
  u32 u = __builtin_bit_cast(u32, f);
  return (u16)((u + 0x7fffu + ((u >> 16) & 1u)) >> 16);
}
DEV float b2f(u16 h) { u32 u = ((u32)h) << 16; return __builtin_bit_cast(float, u); }

DEV void gload16(const void* g, void* l) {  // async global->LDS, 16B/lane
  __builtin_amdgcn_global_load_lds((__attribute__((address_space(1))) void*)(g),
                                   (__attribute__((address_space(3))) void*)(l),
                                   16, 0, 0);
}

DEV f32x4 MFMA(bf16x8 a, bf16x8 b, f32x4 c) {
  return __builtin_amdgcn_mfma_f32_16x16x32_bf16(a, b, c, 0, 0, 0);
}

DEV u32 ldsoff(const void* p) {             // LDS byte offset for ds_* asm
  return (u32)(uintptr_t)(__attribute__((address_space(3))) void*)p;
}
DEV bf16x8 dsr128(u32 a) {                  // compiler-opaque LDS read
  u32x4 d;
  asm volatile("ds_read_b128 %0, %1" : "=v"(d) : "v"(a) : "memory");
  return __builtin_bit_cast(bf16x8, d);
}

// ---------------------------------------------------------------- transpose+cvt (64x64 tiles, vectorized)
__global__ __launch_bounds__(256) void transpose_cvt(const float* __restrict__ W,
                                                     u16* __restrict__ Wt,
                                                     int K, int N) {
  __shared__ float tile[64][65];
  const int n0 = blockIdx.x * 64, k0 = blockIdx.y * 64;
  const int tx = threadIdx.x, ty = threadIdx.y;  // 64 x 4
#pragma unroll
  for (int i = 0; i < 16; ++i) {
    const int row = ty + i * 4;
    tile[row][tx] = W[(size_t)(k0 + row) * N + n0 + tx];
  }
  __syncthreads();
#pragma unroll
  for (int i = 0; i < 8; ++i) {
    const int nrow = ty * 2 + (tx >> 5) + i * 8;
    const int kp = (tx & 31) * 2;
    u16x2 v;
    v[0] = f2b(tile[kp][nrow]);
    v[1] = f2b(tile[kp + 1][nrow]);
    *(u16x2*)&Wt[(size_t)(n0 + nrow) * K + k0 + kp] = v;
  }
}

// ---------------------------------------------------------------- rmsnorm (f32 in, bf16 out), D=4096
__global__ __launch_bounds__(256) void rmsnorm_k(const float* __restrict__ x,
                                                 const float* __restrict__ w,
                                                 u16* __restrict__ o, int D) {
  const int row = blockIdx.x, tid = threadIdx.x;
  const float4* xr = (const float4*)(x + (size_t)row * D);
  const float4* wr = (const float4*)w;
  float4 v[4];
  float ss = 0.f;
#pragma unroll
  for (int i = 0; i < 4; ++i) {
    v[i] = xr[i * 256 + tid];
    ss += v[i].x * v[i].x + v[i].y * v[i].y + v[i].z * v[i].z + v[i].w * v[i].w;
  }
#pragma unroll
  for (int off = 1; off < 64; off <<= 1) ss += __shfl_xor(ss, off, 64);
  __shared__ float red[4];
  if ((tid & 63) == 0) red[tid >> 6] = ss;
  __syncthreads();
  const float tot = red[0] + red[1] + red[2] + red[3];
  const float sc = rsqrtf(tot / (float)D + 1e-6f);
  u16x4* orow = (u16x4*)(o + (size_t)row * D);
#pragma unroll
  for (int i = 0; i < 4; ++i) {
    float4 wv = wr[i * 256 + tid];
    u16x4 p;
    p[0] = f2b(v[i].x * sc * wv.x);
    p[1] = f2b(v[i].y * sc * wv.y);
    p[2] = f2b(v[i].z * sc * wv.z);
    p[3] = f2b(v[i].w * sc * wv.w);
    orow[i * 256 + tid] = p;
  }
}

// ---------------------------------------------------------------- RoPE table
__global__ __launch_bounds__(256) void rope_table(const int* __restrict__ positions,
                                                  float* __restrict__ tab, int BS) {
  const int idx = blockIdx.x * 256 + threadIdx.x;
  if (idx >= BS * 64) return;
  const int bs = idx >> 6, i = idx & 63;
  const float pos = (float)positions[bs];
  const float inv = __expf(-(float)i * (9.210340371976184f / 64.f));
  const float ang = pos * inv;
  float s, c;
  sincosf(ang, &s, &c);
  tab[idx] = c;
  tab[BS * 64 + idx] = s;
}

// ---------------------------------------------------------------- RoPE in-place on bf16 qkv [BS][12288], u16x2-vectorized
__global__ __launch_bounds__(256) void rope_apply(u16* __restrict__ qkv,
                                                  const float* __restrict__ tab, int BS) {
  const int idx = blockIdx.x * 256 + threadIdx.x;  // (bs, h, i-pair)
  if (idx >= BS * 1024) return;
  const int ip = (idx & 31) * 2, h = (idx >> 5) & 31, bs = idx >> 10;
  const float2 c2 = ((const float2*)tab)[bs * 32 + (ip >> 1)];
  const float2 s2 = ((const float2*)(tab + (size_t)BS * 64))[bs * 32 + (ip >> 1)];
  const size_t base = (size_t)bs * 12288 + h * 128 + ip;
  u16x2 a1 = *(const u16x2*)&qkv[base];
  u16x2 a2 = *(const u16x2*)&qkv[base + 64];
  u16x2 b1 = *(const u16x2*)&qkv[base + 4096];
  u16x2 b2 = *(const u16x2*)&qkv[base + 4096 + 64];
  u16x2 r;
  r[0] = f2b(b2f(a1[0]) * c2.x - b2f(a2[0]) * s2.x);
  r[1] = f2b(b2f(a1[1]) * c2.y - b2f(a2[1]) * s2.y);
  *(u16x2*)&qkv[base] = r;
  r[0] = f2b(b2f(a2[0]) * c2.x + b2f(a1[0]) * s2.x);
  r[1] = f2b(b2f(a2[1]) * c2.y + b2f(a1[1]) * s2.y);
  *(u16x2*)&qkv[base + 64] = r;
  r[0] = f2b(b2f(b1[0]) * c2.x - b2f(b2[0]) * s2.x);
  r[1] = f2b(b2f(b1[1]) * c2.y - b2f(b2[1]) * s2.y);
  *(u16x2*)&qkv[base + 4096] = r;
  r[0] = f2b(b2f(b2[0]) * c2.x + b2f(b1[0]) * s2.x);
  r[1] = f2b(b2f(b2[1]) * c2.y + b2f(b1[1]) * s2.y);
  *(u16x2*)&qkv[base + 4096 + 64] = r;
}

// ---------------------------------------------------------------- GEMM 256x256, BK=32, 8 waves, 4-phase (m201 template)
// Replay-verified schedule (r15-r19). N-MAJOR block order (r20): m = wg%16, n = wg/16 -> 16 consecutive
// blocks share one hot weight panel (L2-resident); A (33 MB) streams and fits L3. T1 XCD swizzle on top.
// MODE 0: bf16 out   1: bf16 + f32 bias[col]   2: f32 + f32 resid
template <int MODE>
__global__ __launch_bounds__(512, 2) void gemm256(const u16* __restrict__ A,
                                                  const u16* __restrict__ Bt,
                                                  void* __restrict__ outp,
                                                  const float* __restrict__ bias,
                                                  const float* __restrict__ resid,
                                                  int M, int N, int K) {
  __shared__ __align__(16) u16 As[3 * 8192];
  __shared__ __align__(16) u16 Bs[3 * 8192];     // 96 KiB total
  const int tid = threadIdx.x;
  const int wid = tid >> 6, l = tid & 63;
  const int wm = wid >> 2, wn = wid & 3;          // 2 x 4 waves, each owns 128x64
  const int lr = l & 15, lc = l >> 4;
  const int gx = gridDim.x;
  const int gy = gridDim.y;                       // M/256 = 16
  const int nwg = gx * gy;
  const int orig = blockIdx.y * gx + blockIdx.x;
  const int wg = (orig & 7) * (nwg >> 3) + (orig >> 3);   // T1 (nwg % 8 == 0)
  const int m0 = (wg % gy) * 256, n0 = (wg / gy) * 256;   // n-major: weight panel stays hot

  const int NT = K >> 5;
  const int NI = NT >> 1;

  const int rt = tid >> 2;
  const int ct = (tid & 3) ^ ((rt >> 1) & 3);
  const u16* aS = A + (size_t)(m0 + rt) * K + ct * 8;
  const u16* bS = Bt + (size_t)(n0 + rt) * K + ct * 8;

  auto STG = [&](u16* slot, const u16* src, int tk) {
    gload16(src + tk * 32, slot + wid * 512);
    gload16(src + (size_t)128 * K + tk * 32, slot + 4096 + wid * 512);
  };

  const u32 aBase = ldsoff(As), bBase = ldsoff(Bs);
  auto offA = [&](int slot, int mf) {
    const int r = wm * 128 + mf * 16 + lr;
    return aBase + (u32)slot * 16384u + (u32)(r * 64 + ((lc ^ ((r >> 1) & 3)) * 16));
  };
  auto offB = [&](int slot, int nf) {
    const int r = wn * 64 + nf * 16 + lr;
    return bBase + (u32)slot * 16384u + (u32)(r * 64 + ((lc ^ ((r >> 1) & 3)) * 16));
  };

  f32x4 acc[8][4] = {};

#define BAR()  asm volatile("s_barrier" ::: "memory")
#define VM4()  asm volatile("s_waitcnt vmcnt(4)" ::: "memory")
#define VM0()  asm volatile("s_waitcnt vmcnt(0)" ::: "memory")
#define LGKM0_FENCE() do { asm volatile("s_waitcnt lgkmcnt(0)" ::: "memory"); \
                           __builtin_amdgcn_sched_barrier(0); } while (0)

  STG(&As[0], aS, 0);
  STG(&Bs[0], bS, 0);
  STG(&As[8192], aS, 1);
  STG(&Bs[8192], bS, 1);
  VM4();
  BAR();

  int sa = 0, sb = 1, sc = 2;
  for (int i = 0; i < NI; ++i) {
    const int Tc = 2 * i + 2, Td = 2 * i + 3;
    u16* Aa = &As[sa * 8192]; u16* Ba = &Bs[sa * 8192];
    u16* Ac = &As[sc * 8192]; u16* Bc = &Bs[sc * 8192];
    bf16x8 af[8], b0, b1;
    // ---- P1
#pragma unroll
    for (int mf = 0; mf < 8; ++mf) af[mf] = dsr128(offA(sa, mf));
    b0 = dsr128(offB(sa, 0)); b1 = dsr128(offB(sa, 1));
    if (Tc < NT) STG(Ac, aS, Tc);
    BAR();
    LGKM0_FENCE();
    __builtin_amdgcn_s_setprio(1);
#pragma unroll
    for (int mf = 0; mf < 8; ++mf) {
      acc[mf][0] = MFMA(af[mf], b0, acc[mf][0]);
      acc[mf][1] = MFMA(af[mf], b1, acc[mf][1]);
    }
    __builtin_amdgcn_s_setprio(0);
    BAR();
    // ---- P2
    b0 = dsr128(offB(sa, 2)); b1 = dsr128(offB(sa, 3));
    if (Tc < NT) STG(Bc, bS, Tc);
    BAR();
    LGKM0_FENCE();
    __builtin_amdgcn_s_setprio(1);
#pragma unroll
    for (int mf = 0; mf < 8; ++mf) {
      acc[mf][2] = MFMA(af[mf], b0, acc[mf][2]);
      acc[mf][3] = MFMA(af[mf], b1, acc[mf][3]);
    }
    __builtin_amdgcn_s_setprio(0);
    if (Tc < NT) VM4(); else VM0();   // RACE FIX
    BAR();
    // ---- P3
#pragma unroll
    for (int mf = 0; mf < 8; ++mf) af[mf] = dsr128(offA(sb, mf));
    b0 = dsr128(offB(sb, 0)); b1 = dsr128(offB(sb, 1));
    if (Td < NT) STG(Aa, aS, Td);
    BAR();
    LGKM0_FENCE();
    __builtin_amdgcn_s_setprio(1);
#pragma unroll
    for (int mf = 0; mf < 8; ++mf) {
      acc[mf][0] = MFMA(af[mf], b0, acc[mf][0]);
      acc[mf][1] = MFMA(af[mf], b1, acc[mf][1]);
    }
    __builtin_amdgcn_s_setprio(0);
    BAR();
    // ---- P4
    b0 = dsr128(offB(sb, 2)); b1 = dsr128(offB(sb, 3));
    if (Td < NT) STG(Ba, bS, Td);
    BAR();
    LGKM0_FENCE();
    __builtin_amdgcn_s_setprio(1);
#pragma unroll
    for (int mf = 0; mf < 8; ++mf) {
      acc[mf][2] = MFMA(af[mf], b0, acc[mf][2]);
      acc[mf][3] = MFMA(af[mf], b1, acc[mf][3]);
    }
    __builtin_amdgcn_s_setprio(0);
    if (Td < NT) VM4(); else VM0();   // RACE FIX
    BAR();
    const int t = sc; sc = sb; sb = sa; sa = t;
  }
#undef BAR
#undef VM4
#undef VM0
#undef LGKM0_FENCE

#pragma unroll
  for (int mf = 0; mf < 8; ++mf) {
#pragma unroll
    for (int nf = 0; nf < 4; ++nf) {
      const int gr = m0 + wm * 128 + mf * 16 + lc * 4;
      const int gc = n0 + wn * 64 + nf * 16 + lr;
#pragma unroll
      for (int r = 0; r < 4; ++r) {
        float v = acc[mf][nf][r];
        const size_t idx = (size_t)(gr + r) * N + gc;
        if constexpr (MODE == 0) {
          ((u16*)outp)[idx] = f2b(v);
        } else if constexpr (MODE == 1) {
          ((u16*)outp)[idx] = f2b(v + bias[gc]);
        } else {
          ((float*)outp)[idx] = v + resid[idx];
        }
      }
    }
  }
}

// ---------------------------------------------------------------- FUSED SwiGLU GEMM: act = (A@W1t^T) * silu(A@W2t^T)
// Same verified 4-phase schedule; n-major block order (r20) so the 2 MB W1+W2 panel stays L2-hot
// across 16 consecutive blocks while A streams (fits L3).
__global__ __launch_bounds__(512, 2) void gemm_swiglu(const u16* __restrict__ A,
                                                      const u16* __restrict__ W1t,
                                                      const u16* __restrict__ W2t,
                                                      u16* __restrict__ outp,
                                                      int M, int N, int K) {
  __shared__ __align__(16) u16 As[3 * 8192];
  __shared__ __align__(16) u16 Bs[3 * 8192];
  const int tid = threadIdx.x;
  const int wid = tid >> 6, l = tid & 63;
  const int wm = wid >> 2, wn = wid & 3;
  const int lr = l & 15, lc = l >> 4;
  const int gx = gridDim.x;                       // N/128
  const int gy = gridDim.y;                       // M/256 = 16
  const int nwg = gx * gy;                        // nwg % 8 == 0
  const int orig = blockIdx.y * gx + blockIdx.x;
  const int wg = (orig & 7) * (nwg >> 3) + (orig >> 3);
  const int m0 = (wg % gy) * 256, n0 = (wg / gy) * 128;   // n-major

  const int NT = K >> 5;
  const int NI = NT >> 1;

  const int rt = tid >> 2;
  const int ct = (tid & 3) ^ ((rt >> 1) & 3);
  const u16* aS  = A   + (size_t)(m0 + rt) * K + ct * 8;
  const u16* b1S = W1t + (size_t)(n0 + rt) * K + ct * 8;
  const u16* b2S = W2t + (size_t)(n0 + rt) * K + ct * 8;

  auto STGA = [&](u16* slot, int tk) {
    gload16(aS + tk * 32, slot + wid * 512);
    gload16(aS + (size_t)128 * K + tk * 32, slot + 4096 + wid * 512);
  };
  auto STGB = [&](u16* slot, int tk) {            // rows 0..127 <- W1t, rows 128..255 <- W2t
    gload16(b1S + tk * 32, slot + wid * 512);
    gload16(b2S + tk * 32, slot + 4096 + wid * 512);
  };

  const u32 aBase = ldsoff(As), bBase = ldsoff(Bs);
  auto offA = [&](int slot, int mf) {
    const int r = wm * 128 + mf * 16 + lr;
    return aBase + (u32)slot * 16384u + (u32)(r * 64 + ((lc ^ ((r >> 1) & 3)) * 16));
  };
  auto offB = [&](int slot, int nf) {             // nf 0,1 -> W1 half; nf 2,3 -> W2 half, same cols
    const int r = (nf < 2) ? (wn * 32 + nf * 16 + lr) : (128 + wn * 32 + (nf - 2) * 16 + lr);
    return bBase + (u32)slot * 16384u + (u32)(r * 64 + ((lc ^ ((r >> 1) & 3)) * 16));
  };

  f32x4 acc[8][4] = {};

#define BAR()  asm volatile("s_barrier" ::: "memory")
#define VM4()  asm volatile("s_waitcnt vmcnt(4)" ::: "memory")
#define VM0()  asm volatile("s_waitcnt vmcnt(0)" ::: "memory")
#define LGKM0_FENCE() do { asm volatile("s_waitcnt lgkmcnt(0)" ::: "memory"); \
                           __builtin_amdgcn_sched_barrier(0); } while (0)

  STGA(&As[0], 0);
  STGB(&Bs[0], 0);
  STGA(&As[8192], 1);
  STGB(&Bs[8192], 1);
  VM4();
  BAR();

  int sa = 0, sb = 1, sc = 2;
  for (int i = 0; i < NI; ++i) {
    const int Tc = 2 * i + 2, Td = 2 * i + 3;
    u16* Aa = &As[sa * 8192]; u16* Ba = &Bs[sa * 8192];
    u16* Ac = &As[sc * 8192]; u16* Bc = &Bs[sc * 8192];
    bf16x8 af[8], b0, b1;
    // ---- P1
#pragma unroll
    for (int mf = 0; mf < 8; ++mf) af[mf] = dsr128(offA(sa, mf));
    b0 = dsr128(offB(sa, 0)); b1 = dsr128(offB(sa, 1));
    if (Tc < NT) STGA(Ac, Tc);
    BAR();
    LGKM0_FENCE();
    __builtin_amdgcn_s_setprio(1);
#pragma unroll
    for (int mf = 0; mf < 8; ++mf) {
      acc[mf][0] = MFMA(af[mf], b0, acc[mf][0]);
      acc[mf][1] = MFMA(af[mf], b1, acc[mf][1]);
    }
    __builtin_amdgcn_s_setprio(0);
    BAR();
    // ---- P2
    b0 = dsr128(offB(sa, 2)); b1 = dsr128(offB(sa, 3));
    if (Tc < NT) STGB(Bc, Tc);
    BAR();
    LGKM0_FENCE();
    __builtin_amdgcn_s_setprio(1);
#pragma unroll
    for (int mf = 0; mf < 8; ++mf) {
      acc[mf][2] = MFMA(af[mf], b0, acc[mf][2]);
      acc[mf][3] = MFMA(af[mf], b1, acc[mf][3]);
    }
    __builtin_amdgcn_s_setprio(0);
    if (Tc < NT) VM4(); else VM0();   // RACE FIX (verified r15)
    BAR();
    // ---- P3
#pragma unroll
    for (int mf = 0; mf < 8; ++mf) af[mf] = dsr128(offA(sb, mf));
    b0 = dsr128(offB(sb, 0)); b1 = dsr128(offB(sb, 1));
    if (Td < NT) STGA(Aa, Td);
    BAR();
    LGKM0_FENCE();
    __builtin_amdgcn_s_setprio(1);
#pragma unroll
    for (int mf = 0; mf < 8; ++mf) {
      acc[mf][0] = MFMA(af[mf], b0, acc[mf][0]);
      acc[mf][1] = MFMA(af[mf], b1, acc[mf][1]);
    }
    __builtin_amdgcn_s_setprio(0);
    BAR();
    // ---- P4
    b0 = dsr128(offB(sb, 2)); b1 = dsr128(offB(sb, 3));
    if (Td < NT) STGB(Ba, Td);
    BAR();
    LGKM0_FENCE();
    __builtin_amdgcn_s_setprio(1);
#pragma unroll
    for (int mf = 0; mf < 8; ++mf) {
      acc[mf][2] = MFMA(af[mf], b0, acc[mf][2]);
      acc[mf][3] = MFMA(af[mf], b1, acc[mf][3]);
    }
    __builtin_amdgcn_s_setprio(0);
    if (Td < NT) VM4(); else VM0();   // RACE FIX
    BAR();
    const int t = sc; sc = sb; sb = sa; sa = t;
  }
#undef BAR
#undef VM4
#undef VM0
#undef LGKM0_FENCE

  // epilogue: act = g1 * silu(g2), both in registers (nf and nf+2 hold same columns)
#pragma unroll
  for (int mf = 0; mf < 8; ++mf) {
#pragma unroll
    for (int nf = 0; nf < 2; ++nf) {
      const int gr = m0 + wm * 128 + mf * 16 + lc * 4;
      const int gc = n0 + wn * 32 + nf * 16 + lr;
#pragma unroll
      for (int r = 0; r < 4; ++r) {
        const float g1 = acc[mf][nf][r];
        const float g2 = acc[mf][nf + 2][r];
        const float sv = g2 / (1.f + __expf(-g2));
        outp[(size_t)(gr + r) * N + gc] = f2b(g1 * sv);
      }
    }
  }
}

// ---------------------------------------------------------------- flash attention (causal), HD=128, KVBLK=64
// K : Ks[k][d] at el = k*128 + (d ^ ((k&7)*8))
// V : Vt[d][k] at el = (d*64 + k) ^ ((d&7)*8)
// P : Ps[w][q][k] at el = q*64 + (k ^ ((q&7)*8))
__global__ __launch_bounds__(256) void attn_kernel(const u16* __restrict__ qkv,
                                                   u16* __restrict__ o, int S) {
  const int qtile = gridDim.x - 1 - blockIdx.x;   // largest-work blocks first
  const int bh = blockIdx.y;
  const int b = bh >> 5, h = bh & 31;
  const int q0 = qtile * 64;
  const int tid = threadIdx.x;
  const int w = tid >> 6, l = tid & 63;
  const int lr = l & 15, lc = l >> 4;
  const size_t RS = 12288;
  const float SCALE = 0.08838834764831845f;  // 128^-0.5

  __shared__ __align__(16) u16 Ks[64 * 128];
  __shared__ __align__(16) u16 Vt[128 * 64];
  __shared__ __align__(16) u16 Ps[4][16 * 64];

  bf16x8 qf[4];
  {
    const u16* qp = qkv + (size_t)(b * S + q0 + w * 16 + lr) * RS + h * 128 + 8 * lc;
#pragma unroll
    for (int kc = 0; kc < 4; ++kc) qf[kc] = *(const bf16x8*)(qp + kc * 32);
  }

  float m_[4], ls[4];
  f32x4 O[8] = {};
#pragma unroll
  for (int r = 0; r < 4; ++r) { m_[r] = -3e38f; ls[r] = 0.f; }

  const int nkt = qtile + 1;
  for (int kt = 0; kt < nkt; ++kt) {
    const int k0 = kt * 64;
#pragma unroll
    for (int it = 0; it < 4; ++it) {
      const int eid = it * 256 + tid;
      const int kr = eid >> 4, d0 = (eid & 15) * 8;
      u16x8 k8 = *(const u16x8*)(qkv + (size_t)(b * S + k0 + kr) * RS + 4096 + h * 128 + d0);
      *(u16x8*)&Ks[kr * 128 + (d0 ^ ((kr & 7) * 8))] = k8;
    }
#pragma unroll
    for (int it = 0; it < 4; ++it) {
      const int d0 = (it * 4 + w) * 8;
      u16x8 v8 = *(const u16x8*)(qkv + (size_t)(b * S + k0 + l) * RS + 8192 + h * 128 + d0);
#pragma unroll
      for (int jj = 0; jj < 8; ++jj) {
        const int d = d0 + jj;
        Vt[(d * 64 + l) ^ ((d & 7) * 8)] = v8[jj];
      }
    }
    __syncthreads();

    const int nks = (kt == qtile) ? (w + 1) : 4;
    float sv[4][4];
#pragma unroll
    for (int ks = 0; ks < 4; ++ks) {
      if (ks < nks) {
        const int row = ks * 16 + lr;
        f32x4 sacc = {0.f, 0.f, 0.f, 0.f};
#pragma unroll
        for (int kc = 0; kc < 4; ++kc) {
          bf16x8 kf = *(const bf16x8*)&Ks[row * 128 + ((kc * 32 + 8 * lc) ^ ((lr & 7) * 8))];
          sacc = MFMA(qf[kc], kf, sacc);
        }
        const bool dm = (kt == qtile) && (ks == w);
#pragma unroll
        for (int r = 0; r < 4; ++r) {
          float x = sacc[r] * SCALE;
          if (dm) {
            const int kg = ks * 16 + lr, qg = w * 16 + lc * 4 + r;
            if (kg > qg) x = -3e38f;
          }
          sv[ks][r] = x;
        }
      } else {
#pragma unroll
        for (int r = 0; r < 4; ++r) sv[ks][r] = -3e38f;
      }
    }

    float alpha[4];
#pragma unroll
    for (int r = 0; r < 4; ++r) {
      float pm = fmaxf(fmaxf(sv[0][r], sv[1][r]), fmaxf(sv[2][r], sv[3][r]));
#pragma unroll
      for (int off = 1; off < 16; off <<= 1) pm = fmaxf(pm, __shfl_xor(pm, off, 64));
      const float mn = fmaxf(m_[r], pm);
      alpha[r] = __expf(m_[r] - mn);
      m_[r] = mn;
    }
    float p[4][4];
#pragma unroll
    for (int ks = 0; ks < 4; ++ks)
#pragma unroll
      for (int r = 0; r < 4; ++r) {
        p[ks][r] = __expf(sv[ks][r] - m_[r]);
        const int q = lc * 4 + r, k = ks * 16 + lr;
        Ps[w][q * 64 + (k ^ ((q & 7) * 8))] = f2b(p[ks][r]);
      }
#pragma unroll
    for (int r = 0; r < 4; ++r) {
      float s = p[0][r] + p[1][r] + p[2][r] + p[3][r];
#pragma unroll
      for (int off = 1; off < 16; off <<= 1) s += __shfl_xor(s, off, 64);
      ls[r] = ls[r] * alpha[r] + s;
    }
#pragma unroll
    for (int dt = 0; dt < 8; ++dt)
#pragma unroll
      for (int r = 0; r < 4; ++r) O[dt][r] *= alpha[r];

#pragma unroll
    for (int half = 0; half < 2; ++half) {
      const bf16x8 ap = *(const bf16x8*)&Ps[w][lr * 64 + ((half * 32 + 8 * lc) ^ ((lr & 7) * 8))];
#pragma unroll
      for (int dt = 0; dt < 8; ++dt) {
        const int d = dt * 16 + lr;
        const bf16x8 bv = *(const bf16x8*)&Vt[d * 64 + ((half * 32 + 8 * lc) ^ ((d & 7) * 8))];
        O[dt] = MFMA(ap, bv, O[dt]);
      }
    }
    __syncthreads();
  }

  float inv[4];
#pragma unroll
  for (int r = 0; r < 4; ++r) inv[r] = 1.f / ls[r];
#pragma unroll
  for (int dt = 0; dt < 8; ++dt)
#pragma unroll
    for (int r = 0; r < 4; ++r) {
      const int qg = q0 + w * 16 + lc * 4 + r;
      o[(size_t)(b * S + qg) * 4096 + h * 128 + dt * 16 + lr] = f2b(O[dt][r] * inv[r]);
    }
}

// ---------------------------------------------------------------- launch
extern "C" void kernel_launch(void* const* d_in, const int* in_sizes, int n_in,
                              void* d_out, int out_size, void* d_ws, size_t ws_size,
                              hipStream_t stream) {
  const int*   positions = (const int*)d_in[0];
  const float* hidden    = (const float*)d_in[1];
  const float* ln1       = (const float*)d_in[2];
  const float* ln2       = (const float*)d_in[3];
  const float* Wqkv      = (const float*)d_in[4];
  const float* bqkv      = (const float*)d_in[5];
  const float* Wo        = (const float*)d_in[6];
  const float* W1        = (const float*)d_in[7];
  const float* W2        = (const float*)d_in[8];
  const float* Wout      = (const float*)d_in[9];
  float* out = (float*)d_out;

  const int S = 2048, BS = 4096, D = 4096, FF = 11008, N3 = 12288;

  char* ws = (char*)d_ws;
  size_t off = 0;
  auto alloc = [&](size_t bytes) { void* p = ws + off; off += (bytes + 255) & ~(size_t)255; return p; };
  u16*   WT    = (u16*)alloc((size_t)N3 * D * 2);       // reused for every weight
  u16*   qkv   = (u16*)alloc((size_t)BS * N3 * 2);      // qkv; later reused as W2t (dead after attn)
  u16*   slotH = (u16*)alloc((size_t)BS * D * 2);       // h / attn_out / h3
  float* h2    = (float*)alloc((size_t)BS * D * 4);
  u16*   slotG = (u16*)alloc((size_t)BS * FF * 2);      // act
  float* tab   = (float*)alloc((size_t)2 * BS * 64 * 4);
  if (ws_size < off) return;

  rope_table<<<(BS * 64 + 255) / 256, 256, 0, stream>>>(positions, tab, BS);

  // h = rmsnorm(hidden) ; qkv = h @ Wqkv + b
  transpose_cvt<<<dim3(N3 / 64, D / 64), dim3(64, 4), 0, stream>>>(Wqkv, WT, D, N3);
  rmsnorm_k<<<BS, 256, 0, stream>>>(hidden, ln1, slotH, D);
  gemm256<1><<<dim3(N3 / 256, BS / 256), 512, 0, stream>>>(slotH, WT, qkv, bqkv, nullptr, BS, N3, D);
  rope_apply<<<(BS * 1024) / 256, 256, 0, stream>>>(qkv, tab, BS);

  // attention (64 q-rows per block, 4 waves — r16/r18 verified)
  attn_kernel<<<dim3(S / 64, 64), 256, 0, stream>>>(qkv, slotH, S);

  // h2 = hidden + attn @ Wo
  transpose_cvt<<<dim3(D / 64, D / 64), dim3(64, 4), 0, stream>>>(Wo, WT, D, D);
  gemm256<2><<<dim3(D / 256, BS / 256), 512, 0, stream>>>(slotH, WT, h2, nullptr, hidden, BS, D, D);

  // h3 = rmsnorm(h2) ; act = (h3@W1) * silu(h3@W2) fused ; out = h2 + act@Wout
  rmsnorm_k<<<BS, 256, 0, stream>>>(h2, ln2, slotH, D);
  transpose_cvt<<<dim3(FF / 64, D / 64), dim3(64, 4), 0, stream>>>(W1, WT, D, FF);
  transpose_cvt<<<dim3(FF / 64, D / 64), dim3(64, 4), 0, stream>>>(W2, qkv, D, FF);  // qkv buffer = W2t
  gemm_swiglu<<<dim3(FF / 128, BS / 256), 512, 0, stream>>>(slotH, WT, qkv, slotG, BS, FF, D);
  transpose_cvt<<<dim3(D / 64, FF / 64), dim3(64, 4), 0, stream>>>(Wout, WT, FF, D);
  gemm256<2><<<dim3(D / 256, BS / 256), 512, 0, stream>>>(slotG, WT, out, nullptr, h2, BS, D, FF);
}

// Round 21
// 2231.864 us; speedup vs baseline: 1.0323x; 1.0004x over previous
//
#include <hip/hip_runtime.h>

typedef unsigned short u16;
typedef unsigned int   u32;
typedef __bf16 bf16x8 __attribute__((ext_vector_type(8)));
typedef float  f32x4  __attribute__((ext_vector_type(4)));
typedef unsigned short u16x2 __attribute__((ext_vector_type(2)));
typedef unsigned short u16x4 __attribute__((ext_vector_type(4)));
typedef unsigned short u16x8 __attribute__((ext_vector_type(8)));
typedef unsigned int   u32x4 __attribute__((ext_vector_type(4)));

#define DEV __device__ __forceinline__

DEV u16 f2b(float f) {                      // f32 -> bf16 RNE
  u32 u = __builtin_bit_cast(u32, f);
  return (u16)((u + 0x7fffu + ((u >> 16) & 1u)) >> 16);
}
DEV float b2f(u16 h) { u32 u = ((u32)h) << 16; return __builtin_bit_cast(float, u); }

DEV void gload16(const void* g, void* l) {  // async global->LDS, 16B/lane
  __builtin_amdgcn_global_load_lds((__attribute__((address_space(1))) void*)(g),
                                   (__attribute__((address_space(3))) void*)(l),
                                   16, 0, 0);
}

DEV f32x4 MFMA(bf16x8 a, bf16x8 b, f32x4 c) {
  return __builtin_amdgcn_mfma_f32_16x16x32_bf16(a, b, c, 0, 0, 0);
}

DEV u32 ldsoff(const void* p) {             // LDS byte offset for ds_* asm
  return (u32)(uintptr_t)(__attribute__((address_space(3))) void*)p;
}
DEV bf16x8 dsr128(u32 a) {                  // compiler-opaque LDS read
  u32x4 d;
  asm volatile("ds_read_b128 %0, %1" : "=v"(d) : "v"(a) : "memory");
  return __builtin_bit_cast(bf16x8, d);
}

// ---------------------------------------------------------------- transpose+cvt (64x64 tiles, u16x4 writes)
// W[K][N] f32 -> Wt[N][K] bf16.  Reads: 256B/row.  Writes: u16x4 (8B/lane, 128B per 16-lane group).
__global__ __launch_bounds__(256) void transpose_cvt(const float* __restrict__ W,
                                                     u16* __restrict__ Wt,
                                                     int K, int N) {
  __shared__ float tile[64][65];
  const int n0 = blockIdx.x * 64, k0 = blockIdx.y * 64;
  const int tx = threadIdx.x, ty = threadIdx.y;  // 64 x 4
#pragma unroll
  for (int i = 0; i < 16; ++i) {
    const int row = ty + i * 4;
    tile[row][tx] = W[(size_t)(k0 + row) * N + n0 + tx];
  }
  __syncthreads();
#pragma unroll
  for (int i = 0; i < 4; ++i) {
    const int nr = ty * 4 + (tx >> 4) + i * 16;  // out row (n)
    const int kq = (tx & 15) * 4;                // 4 consecutive k per lane
    u16x4 v;
    v[0] = f2b(tile[kq][nr]);
    v[1] = f2b(tile[kq + 1][nr]);
    v[2] = f2b(tile[kq + 2][nr]);
    v[3] = f2b(tile[kq + 3][nr]);
    *(u16x4*)&Wt[(size_t)(n0 + nr) * K + k0 + kq] = v;
  }
}

// ---------------------------------------------------------------- rmsnorm (f32 in, bf16 out), D=4096
__global__ __launch_bounds__(256) void rmsnorm_k(const float* __restrict__ x,
                                                 const float* __restrict__ w,
                                                 u16* __restrict__ o, int D) {
  const int row = blockIdx.x, tid = threadIdx.x;
  const float4* xr = (const float4*)(x + (size_t)row * D);
  const float4* wr = (const float4*)w;
  float4 v[4];
  float ss = 0.f;
#pragma unroll
  for (int i = 0; i < 4; ++i) {
    v[i] = xr[i * 256 + tid];
    ss += v[i].x * v[i].x + v[i].y * v[i].y + v[i].z * v[i].z + v[i].w * v[i].w;
  }
#pragma unroll
  for (int off = 1; off < 64; off <<= 1) ss += __shfl_xor(ss, off, 64);
  __shared__ float red[4];
  if ((tid & 63) == 0) red[tid >> 6] = ss;
  __syncthreads();
  const float tot = red[0] + red[1] + red[2] + red[3];
  const float sc = rsqrtf(tot / (float)D + 1e-6f);
  u16x4* orow = (u16x4*)(o + (size_t)row * D);
#pragma unroll
  for (int i = 0; i < 4; ++i) {
    float4 wv = wr[i * 256 + tid];
    u16x4 p;
    p[0] = f2b(v[i].x * sc * wv.x);
    p[1] = f2b(v[i].y * sc * wv.y);
    p[2] = f2b(v[i].z * sc * wv.z);
    p[3] = f2b(v[i].w * sc * wv.w);
    orow[i * 256 + tid] = p;
  }
}

// ---------------------------------------------------------------- RoPE table
__global__ __launch_bounds__(256) void rope_table(const int* __restrict__ positions,
                                                  float* __restrict__ tab, int BS) {
  const int idx = blockIdx.x * 256 + threadIdx.x;
  if (idx >= BS * 64) return;
  const int bs = idx >> 6, i = idx & 63;
  const float pos = (float)positions[bs];
  const float inv = __expf(-(float)i * (9.210340371976184f / 64.f));
  const float ang = pos * inv;
  float s, c;
  sincosf(ang, &s, &c);
  tab[idx] = c;
  tab[BS * 64 + idx] = s;
}

// ---------------------------------------------------------------- RoPE in-place on bf16 qkv [BS][12288], u16x2-vectorized
__global__ __launch_bounds__(256) void rope_apply(u16* __restrict__ qkv,
                                                  const float* __restrict__ tab, int BS) {
  const int idx = blockIdx.x * 256 + threadIdx.x;  // (bs, h, i-pair)
  if (idx >= BS * 1024) return;
  const int ip = (idx & 31) * 2, h = (idx >> 5) & 31, bs = idx >> 10;
  const float2 c2 = ((const float2*)tab)[bs * 32 + (ip >> 1)];
  const float2 s2 = ((const float2*)(tab + (size_t)BS * 64))[bs * 32 + (ip >> 1)];
  const size_t base = (size_t)bs * 12288 + h * 128 + ip;
  u16x2 a1 = *(const u16x2*)&qkv[base];
  u16x2 a2 = *(const u16x2*)&qkv[base + 64];
  u16x2 b1 = *(const u16x2*)&qkv[base + 4096];
  u16x2 b2 = *(const u16x2*)&qkv[base + 4096 + 64];
  u16x2 r;
  r[0] = f2b(b2f(a1[0]) * c2.x - b2f(a2[0]) * s2.x);
  r[1] = f2b(b2f(a1[1]) * c2.y - b2f(a2[1]) * s2.y);
  *(u16x2*)&qkv[base] = r;
  r[0] = f2b(b2f(a2[0]) * c2.x + b2f(a1[0]) * s2.x);
  r[1] = f2b(b2f(a2[1]) * c2.y + b2f(a1[1]) * s2.y);
  *(u16x2*)&qkv[base + 64] = r;
  r[0] = f2b(b2f(b1[0]) * c2.x - b2f(b2[0]) * s2.x);
  r[1] = f2b(b2f(b1[1]) * c2.y - b2f(b2[1]) * s2.y);
  *(u16x2*)&qkv[base + 4096] = r;
  r[0] = f2b(b2f(b2[0]) * c2.x + b2f(b1[0]) * s2.x);
  r[1] = f2b(b2f(b2[1]) * c2.y + b2f(b1[1]) * s2.y);
  *(u16x2*)&qkv[base + 4096 + 64] = r;
}

// ---------------------------------------------------------------- GEMM 256x256, BK=32, 8 waves, 4-phase (m201 template)
// Replay-verified schedule (r15-r20). N-major block order: m = wg%gy, n = wg/gy. T1 XCD swizzle on top.
// MODE 0: bf16 out   1: bf16 + f32 bias[col]   2: f32 + f32 resid
template <int MODE>
__global__ __launch_bounds__(512, 2) void gemm256(const u16* __restrict__ A,
                                                  const u16* __restrict__ Bt,
                                                  void* __restrict__ outp,
                                                  const float* __restrict__ bias,
                                                  const float* __restrict__ resid,
                                                  int M, int N, int K) {
  __shared__ __align__(16) u16 As[3 * 8192];
  __shared__ __align__(16) u16 Bs[3 * 8192];     // 96 KiB total
  const int tid = threadIdx.x;
  const int wid = tid >> 6, l = tid & 63;
  const int wm = wid >> 2, wn = wid & 3;          // 2 x 4 waves, each owns 128x64
  const int lr = l & 15, lc = l >> 4;
  const int gx = gridDim.x;
  const int gy = gridDim.y;                       // M/256 = 16
  const int nwg = gx * gy;
  const int orig = blockIdx.y * gx + blockIdx.x;
  const int wg = (orig & 7) * (nwg >> 3) + (orig >> 3);   // T1 (nwg % 8 == 0)
  const int m0 = (wg % gy) * 256, n0 = (wg / gy) * 256;   // n-major: weight panel stays hot

  const int NT = K >> 5;
  const int NI = NT >> 1;

  const int rt = tid >> 2;
  const int ct = (tid & 3) ^ ((rt >> 1) & 3);
  const u16* aS = A + (size_t)(m0 + rt) * K + ct * 8;
  const u16* bS = Bt + (size_t)(n0 + rt) * K + ct * 8;

  auto STG = [&](u16* slot, const u16* src, int tk) {
    gload16(src + tk * 32, slot + wid * 512);
    gload16(src + (size_t)128 * K + tk * 32, slot + 4096 + wid * 512);
  };

  const u32 aBase = ldsoff(As), bBase = ldsoff(Bs);
  auto offA = [&](int slot, int mf) {
    const int r = wm * 128 + mf * 16 + lr;
    return aBase + (u32)slot * 16384u + (u32)(r * 64 + ((lc ^ ((r >> 1) & 3)) * 16));
  };
  auto offB = [&](int slot, int nf) {
    const int r = wn * 64 + nf * 16 + lr;
    return bBase + (u32)slot * 16384u + (u32)(r * 64 + ((lc ^ ((r >> 1) & 3)) * 16));
  };

  f32x4 acc[8][4] = {};

#define BAR()  asm volatile("s_barrier" ::: "memory")
#define VM4()  asm volatile("s_waitcnt vmcnt(4)" ::: "memory")
#define VM0()  asm volatile("s_waitcnt vmcnt(0)" ::: "memory")
#define LGKM0_FENCE() do { asm volatile("s_waitcnt lgkmcnt(0)" ::: "memory"); \
                           __builtin_amdgcn_sched_barrier(0); } while (0)

  STG(&As[0], aS, 0);
  STG(&Bs[0], bS, 0);
  STG(&As[8192], aS, 1);
  STG(&Bs[8192], bS, 1);
  VM4();
  BAR();

  int sa = 0, sb = 1, sc = 2;
  for (int i = 0; i < NI; ++i) {
    const int Tc = 2 * i + 2, Td = 2 * i + 3;
    u16* Aa = &As[sa * 8192]; u16* Ba = &Bs[sa * 8192];
    u16* Ac = &As[sc * 8192]; u16* Bc = &Bs[sc * 8192];
    bf16x8 af[8], b0, b1;
    // ---- P1
#pragma unroll
    for (int mf = 0; mf < 8; ++mf) af[mf] = dsr128(offA(sa, mf));
    b0 = dsr128(offB(sa, 0)); b1 = dsr128(offB(sa, 1));
    if (Tc < NT) STG(Ac, aS, Tc);
    BAR();
    LGKM0_FENCE();
    __builtin_amdgcn_s_setprio(1);
#pragma unroll
    for (int mf = 0; mf < 8; ++mf) {
      acc[mf][0] = MFMA(af[mf], b0, acc[mf][0]);
      acc[mf][1] = MFMA(af[mf], b1, acc[mf][1]);
    }
    __builtin_amdgcn_s_setprio(0);
    BAR();
    // ---- P2
    b0 = dsr128(offB(sa, 2)); b1 = dsr128(offB(sa, 3));
    if (Tc < NT) STG(Bc, bS, Tc);
    BAR();
    LGKM0_FENCE();
    __builtin_amdgcn_s_setprio(1);
#pragma unroll
    for (int mf = 0; mf < 8; ++mf) {
      acc[mf][2] = MFMA(af[mf], b0, acc[mf][2]);
      acc[mf][3] = MFMA(af[mf], b1, acc[mf][3]);
    }
    __builtin_amdgcn_s_setprio(0);
    if (Tc < NT) VM4(); else VM0();   // RACE FIX
    BAR();
    // ---- P3
#pragma unroll
    for (int mf = 0; mf < 8; ++mf) af[mf] = dsr128(offA(sb, mf));
    b0 = dsr128(offB(sb, 0)); b1 = dsr128(offB(sb, 1));
    if (Td < NT) STG(Aa, aS, Td);
    BAR();
    LGKM0_FENCE();
    __builtin_amdgcn_s_setprio(1);
#pragma unroll
    for (int mf = 0; mf < 8; ++mf) {
      acc[mf][0] = MFMA(af[mf], b0, acc[mf][0]);
      acc[mf][1] = MFMA(af[mf], b1, acc[mf][1]);
    }
    __builtin_amdgcn_s_setprio(0);
    BAR();
    // ---- P4
    b0 = dsr128(offB(sb, 2)); b1 = dsr128(offB(sb, 3));
    if (Td < NT) STG(Ba, bS, Td);
    BAR();
    LGKM0_FENCE();
    __builtin_amdgcn_s_setprio(1);
#pragma unroll
    for (int mf = 0; mf < 8; ++mf) {
      acc[mf][2] = MFMA(af[mf], b0, acc[mf][2]);
      acc[mf][3] = MFMA(af[mf], b1, acc[mf][3]);
    }
    __builtin_amdgcn_s_setprio(0);
    if (Td < NT) VM4(); else VM0();   // RACE FIX
    BAR();
    const int t = sc; sc = sb; sb = sa; sa = t;
  }
#undef BAR
#undef VM4
#undef VM0
#undef LGKM0_FENCE

#pragma unroll
  for (int mf = 0; mf < 8; ++mf) {
#pragma unroll
    for (int nf = 0; nf < 4; ++nf) {
      const int gr = m0 + wm * 128 + mf * 16 + lc * 4;
      const int gc = n0 + wn * 64 + nf * 16 + lr;
#pragma unroll
      for (int r = 0; r < 4; ++r) {
        float v = acc[mf][nf][r];
        const size_t idx = (size_t)(gr + r) * N + gc;
        if constexpr (MODE == 0) {
          ((u16*)outp)[idx] = f2b(v);
        } else if constexpr (MODE == 1) {
          ((u16*)outp)[idx] = f2b(v + bias[gc]);
        } else {
          ((float*)outp)[idx] = v + resid[idx];
        }
      }
    }
  }
}

// ---------------------------------------------------------------- FUSED SwiGLU GEMM: act = (A@W1t^T) * silu(A@W2t^T)
// Same verified 4-phase schedule; n-major block order so the 2 MB W1+W2 panel stays L2-hot.
__global__ __launch_bounds__(512, 2) void gemm_swiglu(const u16* __restrict__ A,
                                                      const u16* __restrict__ W1t,
                                                      const u16* __restrict__ W2t,
                                                      u16* __restrict__ outp,
                                                      int M, int N, int K) {
  __shared__ __align__(16) u16 As[3 * 8192];
  __shared__ __align__(16) u16 Bs[3 * 8192];
  const int tid = threadIdx.x;
  const int wid = tid >> 6, l = tid & 63;
  const int wm = wid >> 2, wn = wid & 3;
  const int lr = l & 15, lc = l >> 4;
  const int gx = gridDim.x;                       // N/128
  const int gy = gridDim.y;                       // M/256 = 16
  const int nwg = gx * gy;                        // nwg % 8 == 0
  const int orig = blockIdx.y * gx + blockIdx.x;
  const int wg = (orig & 7) * (nwg >> 3) + (orig >> 3);
  const int m0 = (wg % gy) * 256, n0 = (wg / gy) * 128;   // n-major

  const int NT = K >> 5;
  const int NI = NT >> 1;

  const int rt = tid >> 2;
  const int ct = (tid & 3) ^ ((rt >> 1) & 3);
  const u16* aS  = A   + (size_t)(m0 + rt) * K + ct * 8;
  const u16* b1S = W1t + (size_t)(n0 + rt) * K + ct * 8;
  const u16* b2S = W2t + (size_t)(n0 + rt) * K + ct * 8;

  auto STGA = [&](u16* slot, int tk) {
    gload16(aS + tk * 32, slot + wid * 512);
    gload16(aS + (size_t)128 * K + tk * 32, slot + 4096 + wid * 512);
  };
  auto STGB = [&](u16* slot, int tk) {            // rows 0..127 <- W1t, rows 128..255 <- W2t
    gload16(b1S + tk * 32, slot + wid * 512);
    gload16(b2S + tk * 32, slot + 4096 + wid * 512);
  };

  const u32 aBase = ldsoff(As), bBase = ldsoff(Bs);
  auto offA = [&](int slot, int mf) {
    const int r = wm * 128 + mf * 16 + lr;
    return aBase + (u32)slot * 16384u + (u32)(r * 64 + ((lc ^ ((r >> 1) & 3)) * 16));
  };
  auto offB = [&](int slot, int nf) {             // nf 0,1 -> W1 half; nf 2,3 -> W2 half, same cols
    const int r = (nf < 2) ? (wn * 32 + nf * 16 + lr) : (128 + wn * 32 + (nf - 2) * 16 + lr);
    return bBase + (u32)slot * 16384u + (u32)(r * 64 + ((lc ^ ((r >> 1) & 3)) * 16));
  };

  f32x4 acc[8][4] = {};

#define BAR()  asm volatile("s_barrier" ::: "memory")
#define VM4()  asm volatile("s_waitcnt vmcnt(4)" ::: "memory")
#define VM0()  asm volatile("s_waitcnt vmcnt(0)" ::: "memory")
#define LGKM0_FENCE() do { asm volatile("s_waitcnt lgkmcnt(0)" ::: "memory"); \
                           __builtin_amdgcn_sched_barrier(0); } while (0)

  STGA(&As[0], 0);
  STGB(&Bs[0], 0);
  STGA(&As[8192], 1);
  STGB(&Bs[8192], 1);
  VM4();
  BAR();

  int sa = 0, sb = 1, sc = 2;
  for (int i = 0; i < NI; ++i) {
    const int Tc = 2 * i + 2, Td = 2 * i + 3;
    u16* Aa = &As[sa * 8192]; u16* Ba = &Bs[sa * 8192];
    u16* Ac = &As[sc * 8192]; u16* Bc = &Bs[sc * 8192];
    bf16x8 af[8], b0, b1;
    // ---- P1
#pragma unroll
    for (int mf = 0; mf < 8; ++mf) af[mf] = dsr128(offA(sa, mf));
    b0 = dsr128(offB(sa, 0)); b1 = dsr128(offB(sa, 1));
    if (Tc < NT) STGA(Ac, Tc);
    BAR();
    LGKM0_FENCE();
    __builtin_amdgcn_s_setprio(1);
#pragma unroll
    for (int mf = 0; mf < 8; ++mf) {
      acc[mf][0] = MFMA(af[mf], b0, acc[mf][0]);
      acc[mf][1] = MFMA(af[mf], b1, acc[mf][1]);
    }
    __builtin_amdgcn_s_setprio(0);
    BAR();
    // ---- P2
    b0 = dsr128(offB(sa, 2)); b1 = dsr128(offB(sa, 3));
    if (Tc < NT) STGB(Bc, Tc);
    BAR();
    LGKM0_FENCE();
    __builtin_amdgcn_s_setprio(1);
#pragma unroll
    for (int mf = 0; mf < 8; ++mf) {
      acc[mf][2] = MFMA(af[mf], b0, acc[mf][2]);
      acc[mf][3] = MFMA(af[mf], b1, acc[mf][3]);
    }
    __builtin_amdgcn_s_setprio(0);
    if (Tc < NT) VM4(); else VM0();   // RACE FIX (verified r15)
    BAR();
    // ---- P3
#pragma unroll
    for (int mf = 0; mf < 8; ++mf) af[mf] = dsr128(offA(sb, mf));
    b0 = dsr128(offB(sb, 0)); b1 = dsr128(offB(sb, 1));
    if (Td < NT) STGA(Aa, Td);
    BAR();
    LGKM0_FENCE();
    __builtin_amdgcn_s_setprio(1);
#pragma unroll
    for (int mf = 0; mf < 8; ++mf) {
      acc[mf][0] = MFMA(af[mf], b0, acc[mf][0]);
      acc[mf][1] = MFMA(af[mf], b1, acc[mf][1]);
    }
    __builtin_amdgcn_s_setprio(0);
    BAR();
    // ---- P4
    b0 = dsr128(offB(sb, 2)); b1 = dsr128(offB(sb, 3));
    if (Td < NT) STGB(Ba, Td);
    BAR();
    LGKM0_FENCE();
    __builtin_amdgcn_s_setprio(1);
#pragma unroll
    for (int mf = 0; mf < 8; ++mf) {
      acc[mf][2] = MFMA(af[mf], b0, acc[mf][2]);
      acc[mf][3] = MFMA(af[mf], b1, acc[mf][3]);
    }
    __builtin_amdgcn_s_setprio(0);
    if (Td < NT) VM4(); else VM0();   // RACE FIX
    BAR();
    const int t = sc; sc = sb; sb = sa; sa = t;
  }
#undef BAR
#undef VM4
#undef VM0
#undef LGKM0_FENCE

  // epilogue: act = g1 * silu(g2), both in registers (nf and nf+2 hold same columns)
#pragma unroll
  for (int mf = 0; mf < 8; ++mf) {
#pragma unroll
    for (int nf = 0; nf < 2; ++nf) {
      const int gr = m0 + wm * 128 + mf * 16 + lc * 4;
      const int gc = n0 + wn * 32 + nf * 16 + lr;
#pragma unroll
      for (int r = 0; r < 4; ++r) {
        const float g1 = acc[mf][nf][r];
        const float g2 = acc[mf][nf + 2][r];
        const float sv = g2 / (1.f + __expf(-g2));
        outp[(size_t)(gr + r) * N + gc] = f2b(g1 * sv);
      }
    }
  }
}

// ---------------------------------------------------------------- flash attention (causal), HD=128, KVBLK=64
// K : Ks[k][d] at el = k*128 + (d ^ ((k&7)*8))
// V : Vt[d][k] at el = (d*64 + k) ^ ((d&7)*8)
// P : Ps[w][q][k] at el = q*64 + (k ^ ((q&7)*8))
__global__ __launch_bounds__(256) void attn_kernel(const u16* __restrict__ qkv,
                                                   u16* __restrict__ o, int S) {
  const int qtile = gridDim.x - 1 - blockIdx.x;   // largest-work blocks first
  const int bh = blockIdx.y;
  const int b = bh >> 5, h = bh & 31;
  const int q0 = qtile * 64;
  const int tid = threadIdx.x;
  const int w = tid >> 6, l = tid & 63;
  const int lr = l & 15, lc = l >> 4;
  const size_t RS = 12288;
  const float SCALE = 0.08838834764831845f;  // 128^-0.5

  __shared__ __align__(16) u16 Ks[64 * 128];
  __shared__ __align__(16) u16 Vt[128 * 64];
  __shared__ __align__(16) u16 Ps[4][16 * 64];

  bf16x8 qf[4];
  {
    const u16* qp = qkv + (size_t)(b * S + q0 + w * 16 + lr) * RS + h * 128 + 8 * lc;
#pragma unroll
    for (int kc = 0; kc < 4; ++kc) qf[kc] = *(const bf16x8*)(qp + kc * 32);
  }

  float m_[4], ls[4];
  f32x4 O[8] = {};
#pragma unroll
  for (int r = 0; r < 4; ++r) { m_[r] = -3e38f; ls[r] = 0.f; }

  const int nkt = qtile + 1;
  for (int kt = 0; kt < nkt; ++kt) {
    const int k0 = kt * 64;
#pragma unroll
    for (int it = 0; it < 4; ++it) {
      const int eid = it * 256 + tid;
      const int kr = eid >> 4, d0 = (eid & 15) * 8;
      u16x8 k8 = *(const u16x8*)(qkv + (size_t)(b * S + k0 + kr) * RS + 4096 + h * 128 + d0);
      *(u16x8*)&Ks[kr * 128 + (d0 ^ ((kr & 7) * 8))] = k8;
    }
#pragma unroll
    for (int it = 0; it < 4; ++it) {
      const int d0 = (it * 4 + w) * 8;
      u16x8 v8 = *(const u16x8*)(qkv + (size_t)(b * S + k0 + l) * RS + 8192 + h * 128 + d0);
#pragma unroll
      for (int jj = 0; jj < 8; ++jj) {
        const int d = d0 + jj;
        Vt[(d * 64 + l) ^ ((d & 7) * 8)] = v8[jj];
      }
    }
    __syncthreads();

    const int nks = (kt == qtile) ? (w + 1) : 4;
    float sv[4][4];
#pragma unroll
    for (int ks = 0; ks < 4; ++ks) {
      if (ks < nks) {
        const int row = ks * 16 + lr;
        f32x4 sacc = {0.f, 0.f, 0.f, 0.f};
#pragma unroll
        for (int kc = 0; kc < 4; ++kc) {
          bf16x8 kf = *(const bf16x8*)&Ks[row * 128 + ((kc * 32 + 8 * lc) ^ ((lr & 7) * 8))];
          sacc = MFMA(qf[kc], kf, sacc);
        }
        const bool dm = (kt == qtile) && (ks == w);
#pragma unroll
        for (int r = 0; r < 4; ++r) {
          float x = sacc[r] * SCALE;
          if (dm) {
            const int kg = ks * 16 + lr, qg = w * 16 + lc * 4 + r;
            if (kg > qg) x = -3e38f;
          }
          sv[ks][r] = x;
        }
      } else {
#pragma unroll
        for (int r = 0; r < 4; ++r) sv[ks][r] = -3e38f;
      }
    }

    float alpha[4];
#pragma unroll
    for (int r = 0; r < 4; ++r) {
      float pm = fmaxf(fmaxf(sv[0][r], sv[1][r]), fmaxf(sv[2][r], sv[3][r]));
#pragma unroll
      for (int off = 1; off < 16; off <<= 1) pm = fmaxf(pm, __shfl_xor(pm, off, 64));
      const float mn = fmaxf(m_[r], pm);
      alpha[r] = __expf(m_[r] - mn);
      m_[r] = mn;
    }
    float p[4][4];
#pragma unroll
    for (int ks = 0; ks < 4; ++ks)
#pragma unroll
      for (int r = 0; r < 4; ++r) {
        p[ks][r] = __expf(sv[ks][r] - m_[r]);
        const int q = lc * 4 + r, k = ks * 16 + lr;
        Ps[w][q * 64 + (k ^ ((q & 7) * 8))] = f2b(p[ks][r]);
      }
#pragma unroll
    for (int r = 0; r < 4; ++r) {
      float s = p[0][r] + p[1][r] + p[2][r] + p[3][r];
#pragma unroll
      for (int off = 1; off < 16; off <<= 1) s += __shfl_xor(s, off, 64);
      ls[r] = ls[r] * alpha[r] + s;
    }
#pragma unroll
    for (int dt = 0; dt < 8; ++dt)
#pragma unroll
      for (int r = 0; r < 4; ++r) O[dt][r] *= alpha[r];

#pragma unroll
    for (int half = 0; half < 2; ++half) {
      const bf16x8 ap = *(const bf16x8*)&Ps[w][lr * 64 + ((half * 32 + 8 * lc) ^ ((lr & 7) * 8))];
#pragma unroll
      for (int dt = 0; dt < 8; ++dt) {
        const int d = dt * 16 + lr;
        const bf16x8 bv = *(const bf16x8*)&Vt[d * 64 + ((half * 32 + 8 * lc) ^ ((d & 7) * 8))];
        O[dt] = MFMA(ap, bv, O[dt]);
      }
    }
    __syncthreads();
  }

  float inv[4];
#pragma unroll
  for (int r = 0; r < 4; ++r) inv[r] = 1.f / ls[r];
#pragma unroll
  for (int dt = 0; dt < 8; ++dt)
#pragma unroll
    for (int r = 0; r < 4; ++r) {
      const int qg = q0 + w * 16 + lc * 4 + r;
      o[(size_t)(b * S + qg) * 4096 + h * 128 + dt * 16 + lr] = f2b(O[dt][r] * inv[r]);
    }
}

// ---------------------------------------------------------------- launch
extern "C" void kernel_launch(void* const* d_in, const int* in_sizes, int n_in,
                              void* d_out, int out_size, void* d_ws, size_t ws_size,
                              hipStream_t stream) {
  const int*   positions = (const int*)d_in[0];
  const float* hidden    = (const float*)d_in[1];
  const float* ln1       = (const float*)d_in[2];
  const float* ln2       = (const float*)d_in[3];
  const float* Wqkv      = (const float*)d_in[4];
  const float* bqkv      = (const float*)d_in[5];
  const float* Wo        = (const float*)d_in[6];
  const float* W1        = (const float*)d_in[7];
  const float* W2        = (const float*)d_in[8];
  const float* Wout      = (const float*)d_in[9];
  float* out = (float*)d_out;

  const int S = 2048, BS = 4096, D = 4096, FF = 11008, N3 = 12288;

  char* ws = (char*)d_ws;
  size_t off = 0;
  auto alloc = [&](size_t bytes) { void* p = ws + off; off += (bytes + 255) & ~(size_t)255; return p; };
  u16*   WT    = (u16*)alloc((size_t)N3 * D * 2);       // reused for every weight
  u16*   qkv   = (u16*)alloc((size_t)BS * N3 * 2);      // qkv; later reused as W2t (dead after attn)
  u16*   slotH = (u16*)alloc((size_t)BS * D * 2);       // h / attn_out / h3
  float* h2    = (float*)alloc((size_t)BS * D * 4);
  u16*   slotG = (u16*)alloc((size_t)BS * FF * 2);      // act
  float* tab   = (float*)alloc((size_t)2 * BS * 64 * 4);
  if (ws_size < off) return;

  rope_table<<<(BS * 64 + 255) / 256, 256, 0, stream>>>(positions, tab, BS);

  // h = rmsnorm(hidden) ; qkv = h @ Wqkv + b
  transpose_cvt<<<dim3(N3 / 64, D / 64), dim3(64, 4), 0, stream>>>(Wqkv, WT, D, N3);
  rmsnorm_k<<<BS, 256, 0, stream>>>(hidden, ln1, slotH, D);
  gemm256<1><<<dim3(N3 / 256, BS / 256), 512, 0, stream>>>(slotH, WT, qkv, bqkv, nullptr, BS, N3, D);
  rope_apply<<<(BS * 1024) / 256, 256, 0, stream>>>(qkv, tab, BS);

  // attention (64 q-rows per block, 4 waves — r16/r18 verified)
  attn_kernel<<<dim3(S / 64, 64), 256, 0, stream>>>(qkv, slotH, S);

  // h2 = hidden + attn @ Wo
  transpose_cvt<<<dim3(D / 64, D / 64), dim3(64, 4), 0, stream>>>(Wo, WT, D, D);
  gemm256<2><<<dim3(D / 256, BS / 256), 512, 0, stream>>>(slotH, WT, h2, nullptr, hidden, BS, D, D);

  // h3 = rmsnorm(h2) ; act = (h3@W1) * silu(h3@W2) fused ; out = h2 + act@Wout
  rmsnorm_k<<<BS, 256, 0, stream>>>(h2, ln2, slotH, D);
  transpose_cvt<<<dim3(FF / 64, D / 64), dim3(64, 4), 0, stream>>>(W1, WT, D, FF);
  transpose_cvt<<<dim3(FF / 64, D / 64), dim3(64, 4), 0, stream>>>(W2, qkv, D, FF);  // qkv buffer = W2t
  gemm_swiglu<<<dim3(FF / 128, BS / 256), 512, 0, stream>>>(slotH, WT, qkv, slotG, BS, FF, D);
  transpose_cvt<<<dim3(D / 64, FF / 64), dim3(64, 4), 0, stream>>>(Wout, WT, FF, D);
  gemm256<2><<<dim3(D / 256, BS / 256), 512, 0, stream>>>(slotG, WT, out, nullptr, h2, BS, D, FF);
}